// Round 6
// baseline (161.422 us; speedup 1.0000x reference)
//
#include <hip/hip_runtime.h>

// Problem constants (reference: B=8, T=2048, C=1024, H=64)
#define B_ 8
#define T_ 2048
#define C_ 1024
#define H_ 64

typedef __bf16 bf16x8 __attribute__((ext_vector_type(8)));
typedef float  f32x4  __attribute__((ext_vector_type(4)));
typedef unsigned short u16x8 __attribute__((ext_vector_type(8)));

// round-half-up f32 -> bf16 bits
__device__ __forceinline__ unsigned short f2bf(float f) {
    unsigned u = __builtin_bit_cast(unsigned, f);
    u += 0x8000u;
    return (unsigned short)(u >> 16);
}

__device__ __forceinline__ float bf2f(unsigned short v) {
    unsigned u = ((unsigned)v) << 16;
    return __builtin_bit_cast(float, u);
}

__device__ __forceinline__ unsigned pack2(float lo, float hi) {
    unsigned a = __builtin_bit_cast(unsigned, lo) + 0x8000u;
    unsigned b = __builtin_bit_cast(unsigned, hi) + 0x8000u;
    return (a >> 16) | (b & 0xffff0000u);
}

union U8 { unsigned u32[4]; u16x8 v; };

__device__ __forceinline__ u16x8 cvt8(float4 f0, float4 f1) {
    U8 r;
    r.u32[0] = pack2(f0.x, f0.y);
    r.u32[1] = pack2(f0.z, f0.w);
    r.u32[2] = pack2(f1.x, f1.y);
    r.u32[3] = pack2(f1.z, f1.w);
    return r.v;
}

__device__ __forceinline__ bf16x8 load8_bf(const unsigned short* p) {
    return __builtin_bit_cast(bf16x8, *(const u16x8*)p);
}

// Async global->LDS, 16B per lane, no destination VGPRs (vmcnt-counted).
__device__ __forceinline__ void gload_lds16(const float* g, float* l) {
    __builtin_amdgcn_global_load_lds(
        (const __attribute__((address_space(1))) unsigned int*)g,
        (__attribute__((address_space(3))) unsigned int*)l, 16, 0, 0);
}

// Fragment-major layouts (contiguous 1KB-per-wave loads):
//   Qf/Kf[b][t16][part][l16*32 + quad*8 + j]   (t16 = seq/16, part = h/32)
//   Vf[b][s32][ht][l16*32 + quad*8 + j]        (s32 = seq/32, ht = h/16)
//   Wtf[nt][kk][l16*32 + quad*8 + j]           (nt = ncol/16 of 192, kk = c/32)

// ---------------------------------------------------------------------------
// Kernel 0: pack Wq,Wk,Wv (fp32 [C][H]) straight into fragment-major Wtf.
// ---------------------------------------------------------------------------
__global__ void cast_weights(const float* __restrict__ Wq,
                             const float* __restrict__ Wk,
                             const float* __restrict__ Wv,
                             unsigned short* __restrict__ Wtf) {
    int idx = blockIdx.x * blockDim.x + threadIdx.x;   // 0 .. 192*1024-1
    int n   = idx % 192;        // global out col
    int c   = idx / 192;        // k index
    int w   = n >> 6;
    int h   = n & 63;
    const float* W = (w == 0) ? Wq : (w == 1) ? Wk : Wv;
    int nt = n >> 4, l16 = n & 15;
    int kk = c >> 5, quad = (c >> 3) & 3, j = c & 7;
    Wtf[(size_t)(nt * 32 + kk) * 512 + l16 * 32 + quad * 8 + j] =
        f2bf(W[(size_t)c * H_ + h]);
}

// ---------------------------------------------------------------------------
// Kernel 1: fused QKV projection, v13 — B-STATIONARY, VMEM-FREE K-LOOP.
// v8-v12 all hit 44-50us. The invariant across all five: per-k-step Wtf
// B-loads as vmem reads in the k-loop (402 MB of L2 traffic + an in-order
// vmcnt dependency the compiler drains every step). v13 removes vmem from
// the k-loop entirely:
//  - block = 768 threads (12 waves); wave w permanently owns n-tile w.
//    Its whole-K B panel = 32 x bf16x8 = 128 VGPRs, loaded ONCE per block
//    (32 coalesced 1KB loads). B L2 traffic: 402 -> 96 MB.
//  - x staged fp32 by global_load_lds DMA (0 VGPRs) into F; ONE cvt pass
//    writes bf16 A2 (XOR-swizzled, v9-verified layout). cvt cost paid once,
//    not 12x per wave.
//  - k-loop per wave: 32 x (ds_read_b128 + MFMA) — no vmem, so the next
//    tile's DMA (issued before the k-loop) is never drained mid-loop; the
//    post-loop __syncthreads IS the stage-complete fence.
//  - acc = ONE f32x4/wave (v12's regalloc blowup came from 3 accs x 4-tile
//    persistent loop + prefetch in one body; this body is minimal).
// Grid = 256 blocks x 64 rows (4 tiles of 16). LDS = F 64K + A2 2x32K +
// E 6K = 134 KB -> 1 block/CU, 12 waves = 3/SIMD via launch_bounds(768,3).
// ---------------------------------------------------------------------------
__global__ __launch_bounds__(768, 3) void qkv_proj(
        const float* __restrict__ x,
        const unsigned short* __restrict__ Wtf,
        unsigned short* __restrict__ Qf,
        unsigned short* __restrict__ Kf,
        unsigned short* __restrict__ Vf) {
    __shared__ __attribute__((aligned(16))) float F[16 * 1024];            // 64 KB
    __shared__ __attribute__((aligned(16))) unsigned short A2[2][16 * 1024]; // 64 KB
    __shared__ __attribute__((aligned(16))) unsigned short E[3072];        // 6 KB

    const int tid  = threadIdx.x;
    const int w    = tid >> 6;           // wave 0..11 == n-tile
    const int lane = tid & 63;
    const int l16  = lane & 15;
    const int quad = lane >> 4;
    const size_t rblk = (size_t)blockIdx.x * 64;
    const int bb   = (int)(rblk >> 11);
    const int loff = l16 * 32 + quad * 8;
    const int xsw  = l16 & 7;

    // ---- B panel: wave w's n-tile, whole K, in registers (128 VGPR) ----
    bf16x8 Bf[32];
#pragma unroll
    for (int kk = 0; kk < 32; kk++)
        Bf[kk] = load8_bf(Wtf + (size_t)(w * 32 + kk) * 512 + loff);

    // ---- DMA tile 0 -> F (waves 0..7, 8 x 1KB issues each; linear dest) ----
    if (w < 8) {
#pragma unroll
        for (int q = 0; q < 8; q++) {
            int j   = w * 8 + q;         // 0..63
            int row = j >> 2;            // 0..15
            int G0  = (j & 3) * 64;      // float4-granule base in the row
            gload_lds16(x + (rblk + row) * C_ + (size_t)(G0 + lane) * 4,
                        &F[row * 1024 + G0 * 4]);
        }
    }
    __syncthreads();                     // B + DMA drained

    // ---- cvt pass: F (fp32) -> A2[0] (bf16, XOR-swizzled granule8) ----
    if (tid < 512) {
#pragma unroll
        for (int jj = 0; jj < 4; jj++) {
            int p = jj * 512 + tid;      // granule8 0..2047
            int r = p >> 7, s = p & 127;
            float4 f0 = *(const float4*)(&F[p * 8]);
            float4 f1 = *(const float4*)(&F[p * 8 + 4]);
            *(u16x8*)(&A2[0][r * 1024 + (s ^ (r & 7)) * 8]) = cvt8(f0, f1);
        }
    }
    __syncthreads();

    for (int t = 0; t < 4; t++) {
        // issue DMA for tile t+1 (flies under the vmem-free k-loop)
        if (t < 3 && w < 8) {
            const size_t rnext = rblk + (size_t)(t + 1) * 16;
#pragma unroll
            for (int q = 0; q < 8; q++) {
                int j   = w * 8 + q;
                int row = j >> 2;
                int G0  = (j & 3) * 64;
                gload_lds16(x + (rnext + row) * C_ + (size_t)(G0 + lane) * 4,
                            &F[row * 1024 + G0 * 4]);
            }
        }

        // ---- k-loop: 32 x (1 ds_read_b128 + 1 MFMA), zero vmem ----
        const unsigned short* Ar = &A2[t & 1][l16 * 1024];
        f32x4 acc = (f32x4){0.f, 0.f, 0.f, 0.f};
#pragma unroll
        for (int kk = 0; kk < 32; kk++) {
            bf16x8 a0 = load8_bf(Ar + ((kk * 4 + quad) ^ xsw) * 8);
            acc = __builtin_amdgcn_mfma_f32_16x16x32_bf16(a0, Bf[kk], acc, 0, 0, 0);
        }
        __syncthreads();                 // A2[t&1] reads done; DMA t+1 drained

        // ---- cvt tile t+1 into the other A2 buffer ----
        if (t < 3 && tid < 512) {
#pragma unroll
            for (int jj = 0; jj < 4; jj++) {
                int p = jj * 512 + tid;
                int r = p >> 7, s = p & 127;
                float4 f0 = *(const float4*)(&F[p * 8]);
                float4 f1 = *(const float4*)(&F[p * 8 + 4]);
                *(u16x8*)(&A2[(t + 1) & 1][r * 1024 + (s ^ (r & 7)) * 8]) = cvt8(f0, f1);
            }
        }

        // ---- assemble E for this wave's n-tile (v11-verified layout) ----
        const int tloc0  = (int)((rblk + (size_t)t * 16) & (T_ - 1));
        const int t16_0  = tloc0 >> 4;
        const int s32    = tloc0 >> 5;
        const int half16 = t16_0 & 1;
        {
            const int nt = w;
#pragma unroll
            for (int r = 0; r < 4; r++) {
                unsigned short bv = f2bf(acc[r]);
                int off;
                if (nt < 4) {                // Q, part = nt>>1
                    off = (nt >> 1) * 512 + (quad * 4 + r) * 32 +
                          ((nt & 1) * 2 + (l16 >> 3)) * 8 + (l16 & 7);
                } else if (nt < 8) {         // K
                    int nk = nt - 4;
                    off = 1024 + (nk >> 1) * 512 + (quad * 4 + r) * 32 +
                          ((nk & 1) * 2 + (l16 >> 3)) * 8 + (l16 & 7);
                } else {                     // V (transposed): h-major, s minor
                    int ht = nt - 8;
                    off = 2048 + ht * 256 + l16 * 16 + quad * 4 + r;
                }
                E[off] = bv;
            }
        }
        __syncthreads();                 // E complete; cvt t+1 complete

        // ---- copy-out tile t (overlaps next iteration's k-loop) ----
        if (tid < 256) {                 // Q/K: 4 chunks x 64 granules
            int ch = tid >> 6;
            int g  = tid & 63;
            unsigned short* dst = (ch < 2) ? Qf : Kf;
            int part = ch & 1;
            dst += ((size_t)(bb * 128 + t16_0) * 2 + part) * 512;
            *(u16x8*)(dst + g * 8) = *(const u16x8*)(&E[ch * 512 + g * 8]);
        } else if (tid < 384) {          // V: 4 ht x 16 h x 2 granules
            int rr2  = tid - 256;
            int ht   = rr2 >> 5;
            int rr   = rr2 & 31;
            int l16v = rr >> 1;
            int hh   = rr & 1;
            unsigned short* dst = Vf + ((size_t)(bb * 64 + s32) * 4 + ht) * 512
                                  + l16v * 32 + half16 * 16 + hh * 8;
            *(u16x8*)dst = *(const u16x8*)(&E[2048 + ht * 256 + l16v * 16 + hh * 8]);
        }
        // next k-loop reads A2[(t+1)&1] (fenced above); E reads complete
        // before the next post-k-loop barrier's lgkmcnt(0) -> race-free.
    }
}

// ---------------------------------------------------------------------------
// Kernel 2: flash attention, v8 (32 q-rows/block, 4-way KV split).
// Grid = B * T/32 = 512 blocks x 256 threads, XCD batch-affinity (b = blk&7).
// Two q-groups per block share every K/V fragment load (2x arithmetic
// intensity) and total KV tile re-read traffic halves vs v7.
// ---------------------------------------------------------------------------
#define PROW 33   // u32 per P^T row
#define OMS2 66   // u16 per O-merge row

__global__ __launch_bounds__(256) void attn(
        const unsigned short* __restrict__ Qf,
        const unsigned short* __restrict__ Kf,
        const unsigned short* __restrict__ Vf,
        float* __restrict__ out) {
    __shared__ unsigned int ps_[4 * 32 * PROW];     // 16.9 KB
    __shared__ unsigned short Om_[4 * 32 * OMS2];   // 16.9 KB
    __shared__ float mred_[4][32];
    __shared__ float lred_[4][32];

    const int tid  = threadIdx.x;
    const int wave = tid >> 6;            // KV-split index 0..3
    const int lane = tid & 63;
    const int l16  = lane & 15;
    const int quad = lane >> 4;
    const int b    = blockIdx.x & 7;      // XCD-affinity: batch = XCD
    const int qt32 = blockIdx.x >> 3;     // 0..63
    const int q0   = qt32 * 32;
    const int tdiag = qt32 >> 1;          // diagonal 64-key tile index

    const int loff = l16 * 32 + quad * 8;

    // Q as B-operand, two q-groups
    bf16x8 qf[2][2];
#pragma unroll
    for (int qg = 0; qg < 2; qg++) {
        const unsigned short* Qfb = Qf + (size_t)((b * 128 + qt32 * 2 + qg) * 2) * 512;
        qf[qg][0] = load8_bf(Qfb + loff);
        qf[qg][1] = load8_bf(Qfb + 512 + loff);
    }

    f32x4 o[8];   // [qg*4 + ht]
#pragma unroll
    for (int i = 0; i < 8; i++) o[i] = (f32x4){0.f, 0.f, 0.f, 0.f};
    float m_run[2] = {-1e30f, -1e30f}, l_run[2] = {0.f, 0.f};

    const float scale = 0.125f;  // 1/sqrt(H)
    const unsigned short* Kfb = Kf + (size_t)b * 128 * 1024;
    const unsigned short* Vfb = Vf + (size_t)b * 64 * 2048;
    unsigned int* Pw = &ps_[wave * 32 * PROW];

    for (int t = wave; t <= tdiag; t += 4) {
        // V^T A-frags: contiguous 1KB loads, issued EARLY (softmax-independent)
        bf16x8 vf[8];
#pragma unroll
        for (int ks = 0; ks < 2; ks++)
#pragma unroll
            for (int ht = 0; ht < 4; ht++)
                vf[ht * 2 + ks] = load8_bf(
                    Vfb + ((size_t)(t * 2 + ks) * 4 + ht) * 512 + loff);

        // S^T = K * Q^T for both q-groups (K frags shared)
        f32x4 s[2][4];
#pragma unroll
        for (int nt = 0; nt < 4; nt++) {
            const unsigned short* kp = Kfb + (size_t)(t * 4 + nt) * 1024;
            bf16x8 kf0 = load8_bf(kp + loff);
            bf16x8 kf1 = load8_bf(kp + 512 + loff);
#pragma unroll
            for (int qg = 0; qg < 2; qg++) {
                f32x4 z = (f32x4){0.f, 0.f, 0.f, 0.f};
                z = __builtin_amdgcn_mfma_f32_16x16x32_bf16(kf0, qf[qg][0], z, 0, 0, 0);
                z = __builtin_amdgcn_mfma_f32_16x16x32_bf16(kf1, qf[qg][1], z, 0, 0, 0);
                s[qg][nt] = z;   // S^T[s = t*64+nt*16+quad*4+r][q = q0+qg*16+l16]
            }
        }

#pragma unroll
        for (int qg = 0; qg < 2; qg++)
#pragma unroll
            for (int nt = 0; nt < 4; nt++)
#pragma unroll
                for (int r = 0; r < 4; r++) s[qg][nt][r] *= scale;

        if (t == tdiag) {   // causal: mask s > q
#pragma unroll
            for (int qg = 0; qg < 2; qg++) {
                int q = q0 + qg * 16 + l16;
#pragma unroll
                for (int nt = 0; nt < 4; nt++)
#pragma unroll
                    for (int r = 0; r < 4; r++) {
                        int key = t * 64 + nt * 16 + quad * 4 + r;
                        if (key > q) s[qg][nt][r] = -1e30f;
                    }
            }
        }

        // per-lane softmax per q-group: in-lane tree + 2 cross-quad shuffles
#pragma unroll
        for (int qg = 0; qg < 2; qg++) {
            float m0 = fmaxf(fmaxf(s[qg][0][0], s[qg][0][1]), fmaxf(s[qg][0][2], s[qg][0][3]));
            float m1 = fmaxf(fmaxf(s[qg][1][0], s[qg][1][1]), fmaxf(s[qg][1][2], s[qg][1][3]));
            float m2 = fmaxf(fmaxf(s[qg][2][0], s[qg][2][1]), fmaxf(s[qg][2][2], s[qg][2][3]));
            float m3 = fmaxf(fmaxf(s[qg][3][0], s[qg][3][1]), fmaxf(s[qg][3][2], s[qg][3][3]));
            float mx = fmaxf(fmaxf(m0, m1), fmaxf(m2, m3));
            mx = fmaxf(mx, __shfl_xor(mx, 16));
            mx = fmaxf(mx, __shfl_xor(mx, 32));
            const float m_new = fmaxf(m_run[qg], mx);
            const float alpha = __expf(m_run[qg] - m_new);
            m_run[qg] = m_new;

            float rs = 0.f;
#pragma unroll
            for (int nt = 0; nt < 4; nt++) {
#pragma unroll
                for (int i = 0; i < 2; i++) {
                    float p0 = __expf(s[qg][nt][2 * i]     - m_new);
                    float p1 = __expf(s[qg][nt][2 * i + 1] - m_new);
                    rs += p0 + p1;
                    Pw[(qg * 16 + l16) * PROW + nt * 8 + quad * 2 + i] = pack2(p0, p1);
                }
            }
            rs += __shfl_xor(rs, 16);
            rs += __shfl_xor(rs, 32);
            l_run[qg] = l_run[qg] * alpha + rs;

#pragma unroll
            for (int ht = 0; ht < 4; ht++)
#pragma unroll
                for (int r = 0; r < 4; r++) o[qg * 4 + ht][r] *= alpha;
        }

        // O^T += V^T * P^T (V frags shared across q-groups)
#pragma unroll
        for (int ks = 0; ks < 2; ks++) {
#pragma unroll
            for (int qg = 0; qg < 2; qg++) {
                bf16x8 pB = __builtin_bit_cast(bf16x8,
                    *(const u16x8*)(&Pw[(qg * 16 + l16) * PROW + ks * 16 + quad * 4]));
#pragma unroll
                for (int ht = 0; ht < 4; ht++)
                    o[qg * 4 + ht] = __builtin_amdgcn_mfma_f32_16x16x32_bf16(
                        vf[ht * 2 + ks], pB, o[qg * 4 + ht], 0, 0, 0);
            }
        }
    }

    // ---- 4-way LSE merge (O partials bf16) ----
#pragma unroll
    for (int qg = 0; qg < 2; qg++) {
#pragma unroll
        for (int ht = 0; ht < 4; ht++)
#pragma unroll
            for (int r = 0; r < 4; r++)
                Om_[(wave * 32 + qg * 16 + l16) * OMS2 + ht * 16 + quad * 4 + r] =
                    f2bf(o[qg * 4 + ht][r]);
        if (quad == 0) {
            mred_[wave][qg * 16 + l16] = m_run[qg];
            lred_[wave][qg * 16 + l16] = l_run[qg];
        }
    }
    __syncthreads();

    // finalize: thread -> (q, h); coalesced out write
    const int hcol = tid & 63;
    const int qr0  = tid >> 6;   // 0..3
#pragma unroll
    for (int qq = 0; qq < 8; qq++) {
        const int q = qr0 + qq * 4;
        float M = -1e30f;
#pragma unroll
        for (int w = 0; w < 4; w++) M = fmaxf(M, mred_[w][q]);
        float lt = 0.f, ov = 0.f;
#pragma unroll
        for (int w = 0; w < 4; w++) {
            float e = __expf(mred_[w][q] - M);
            lt += e * lred_[w][q];
            ov += e * bf2f(Om_[(w * 32 + q) * OMS2 + hcol]);
        }
        out[((size_t)b * T_ + q0 + q) * H_ + hcol] = ov / lt;
    }
}

// ---------------------------------------------------------------------------
extern "C" void kernel_launch(void* const* d_in, const int* in_sizes, int n_in,
                              void* d_out, int out_size, void* d_ws, size_t ws_size,
                              hipStream_t stream) {
    const float* x  = (const float*)d_in[0];
    const float* Wq = (const float*)d_in[1];
    const float* Wk = (const float*)d_in[2];
    const float* Wv = (const float*)d_in[3];
    float* out = (float*)d_out;

    unsigned short* Qf  = (unsigned short*)d_ws;
    unsigned short* Kf  = Qf + (size_t)B_ * T_ * H_;
    unsigned short* Vf  = Kf + (size_t)B_ * T_ * H_;
    unsigned short* Wtf = Vf + (size_t)B_ * T_ * H_;

    cast_weights<<<(192 * C_) / 256, 256, 0, stream>>>(Wq, Wk, Wv, Wtf);
    qkv_proj<<<B_ * T_ / 64, 768, 0, stream>>>(x, Wtf, Qf, Kf, Vf);
    attn<<<B_ * (T_ / 32), 256, 0, stream>>>(Qf, Kf, Vf, out);
}

// Round 7
// 142.799 us; speedup vs baseline: 1.1304x; 1.1304x over previous
//
#include <hip/hip_runtime.h>

// Problem constants (reference: B=8, T=2048, C=1024, H=64)
#define B_ 8
#define T_ 2048
#define C_ 1024
#define H_ 64

typedef __bf16 bf16x8 __attribute__((ext_vector_type(8)));
typedef float  f32x4  __attribute__((ext_vector_type(4)));
typedef unsigned short u16x8 __attribute__((ext_vector_type(8)));

// round-half-up f32 -> bf16 bits
__device__ __forceinline__ unsigned short f2bf(float f) {
    unsigned u = __builtin_bit_cast(unsigned, f);
    u += 0x8000u;
    return (unsigned short)(u >> 16);
}

__device__ __forceinline__ float bf2f(unsigned short v) {
    unsigned u = ((unsigned)v) << 16;
    return __builtin_bit_cast(float, u);
}

__device__ __forceinline__ unsigned pack2(float lo, float hi) {
    unsigned a = __builtin_bit_cast(unsigned, lo) + 0x8000u;
    unsigned b = __builtin_bit_cast(unsigned, hi) + 0x8000u;
    return (a >> 16) | (b & 0xffff0000u);
}

union U8 { unsigned u32[4]; u16x8 v; };

__device__ __forceinline__ u16x8 cvt8(float4 f0, float4 f1) {
    U8 r;
    r.u32[0] = pack2(f0.x, f0.y);
    r.u32[1] = pack2(f0.z, f0.w);
    r.u32[2] = pack2(f1.x, f1.y);
    r.u32[3] = pack2(f1.z, f1.w);
    return r.v;
}

__device__ __forceinline__ bf16x8 load8_bf(const unsigned short* p) {
    return __builtin_bit_cast(bf16x8, *(const u16x8*)p);
}

// Async global->LDS, 16B per lane, no destination VGPRs (vmcnt-counted).
// Dest = wave-uniform base + lane*16 (linear); source addr is per-lane.
__device__ __forceinline__ void gload_lds16(const float* g, float* l) {
    __builtin_amdgcn_global_load_lds(
        (const __attribute__((address_space(1))) unsigned int*)g,
        (__attribute__((address_space(3))) unsigned int*)l, 16, 0, 0);
}

// Fragment-major layouts (contiguous 1KB-per-wave loads):
//   Qf/Kf[b][t16][part][l16*32 + quad*8 + j]   (t16 = seq/16, part = h/32)
//   Vf[b][s32][ht][l16*32 + quad*8 + j]        (s32 = seq/32, ht = h/16)
//   Wtf[nt][kk][l16*32 + quad*8 + j]           (nt = ncol/16 of 192, kk = c/32)

// ---------------------------------------------------------------------------
// Kernel 0: pack Wq,Wk,Wv (fp32 [C][H]) straight into fragment-major Wtf.
// ---------------------------------------------------------------------------
__global__ void cast_weights(const float* __restrict__ Wq,
                             const float* __restrict__ Wk,
                             const float* __restrict__ Wv,
                             unsigned short* __restrict__ Wtf) {
    int idx = blockIdx.x * blockDim.x + threadIdx.x;   // 0 .. 192*1024-1
    int n   = idx % 192;        // global out col
    int c   = idx / 192;        // k index
    int w   = n >> 6;
    int h   = n & 63;
    const float* W = (w == 0) ? Wq : (w == 1) ? Wk : Wv;
    int nt = n >> 4, l16 = n & 15;
    int kk = c >> 5, quad = (c >> 3) & 3, j = c & 7;
    Wtf[(size_t)(nt * 32 + kk) * 512 + l16 * 32 + quad * 8 + j] =
        f2bf(W[(size_t)c * H_ + h]);
}

// ---------------------------------------------------------------------------
// Kernel 1: fused QKV projection, v14 — canonical double-buffered LDS GEMM.
// History: v8-v12 kept per-k-step Wtf loads as vmem reads -> ~1150 cy of
// exposed L2 latency per k-step (compiler waits per load, no cross-step
// overlap); v13 tried B-in-registers and SPILLED (VGPR 84, WRITE_SIZE 47MB).
// v14 = the Sec.5/m97 structure: BOTH operands DMA'd to LDS per k-chunk,
// double-buffered; the k-loop is pure LDS+MFMA (no vmem at all), and the
// __syncthreads vmcnt(0) drain is the intended chunk fence.
//   block = 64 rows x 192 cols, 512 thr (8 waves = 4 m-strips x 2 n-halves)
//   grid  = 256 = 1 block/CU -> NO sequential blocks per CU
//   chunk = 64 k: A 64x64 fp32 (16 KB, XOR-swizzled source), B 192x64 bf16
//           (24 KB, linear); 40 DMA issues/chunk (5 per wave), dbuf.
//   per chunk per wave: 4 ds_read A + cvt + 12 ds_read B + 12 MFMA
//   LDS 80 KB (A 2x16 | B 2x24); epilogue E (24 KB) overlays dead A region.
//   acc state = 6 x f32x4 = 24 VGPR -> nothing to spill.
// ---------------------------------------------------------------------------
#define NCH 16   // K chunks (1024 / 64)

__global__ __launch_bounds__(512, 2) void qkv_proj(
        const float* __restrict__ x,
        const unsigned short* __restrict__ Wtf,
        unsigned short* __restrict__ Qf,
        unsigned short* __restrict__ Kf,
        unsigned short* __restrict__ Vf) {
    __shared__ __attribute__((aligned(16))) char smem[81920];   // 80 KB
    float* Abuf          = (float*)smem;                        // 2 x 4096 f32
    unsigned short* Bbuf = (unsigned short*)(smem + 32768);     // 2 x 12288 u16
    unsigned short* E    = (unsigned short*)smem;               // 2 x 6144 u16

    const int tid   = threadIdx.x;
    const int w     = tid >> 6;        // wave 0..7
    const int strip = w & 3;           // m-strip (16 rows)
    const int nh    = w >> 2;          // n-half (6 n-tiles = 96 cols)
    const int lane  = tid & 63;
    const int l16   = lane & 15;
    const int quad  = lane >> 4;
    const size_t rblk = (size_t)blockIdx.x * 64;
    const int bb    = (int)(rblk >> 11);
    const int tloc0 = (int)(rblk & (T_ - 1));
    const int t16_0 = tloc0 >> 4;
    const int s32_0 = tloc0 >> 5;
    const int loff  = l16 * 32 + quad * 8;
    const int xsw   = l16 & 7;

    // ---- stage chunk c into buffer buf: 40 x 1KB issues, 5 per wave ----
    auto stage = [&](int c, int buf) {
#pragma unroll
        for (int q = 0; q < 5; q++) {
            int j = w * 5 + q;                 // 0..39
            if (j < 16) {                      // A: 64x64 fp32, swz source
                int row  = j * 4 + (lane >> 4);    // 0..63 (block-local)
                int slot = lane & 15;              // 16B slot within row
                int g    = slot ^ (row & 7);       // global granule16
                gload_lds16(x + (rblk + row) * C_ + c * 64 + g * 4,
                            Abuf + buf * 4096 + j * 256);
            } else {                           // B: 24 x 1KB frag blocks
                int jb = j - 16;               // 0..23
                int nt = jb >> 1, kkl = jb & 1;
                gload_lds16(
                    (const float*)(Wtf + ((size_t)nt * 32 + c * 2 + kkl) * 512
                                   + (size_t)lane * 8),
                    (float*)((char*)(Bbuf + buf * 12288) + jb * 1024));
            }
        }
    };

    f32x4 acc[6];
#pragma unroll
    for (int i = 0; i < 6; i++) acc[i] = (f32x4){0.f, 0.f, 0.f, 0.f};

    stage(0, 0);
    __syncthreads();                   // chunk 0 landed

    for (int c = 0; c < NCH; c++) {
        if (c < NCH - 1) stage(c + 1, (c + 1) & 1);   // flies under compute

        const float* Ab = Abuf + (c & 1) * 4096 + (strip * 16 + l16) * 64;
        const unsigned short* Bb = Bbuf + (c & 1) * 12288;
#pragma unroll
        for (int kk = 0; kk < 2; kk++) {
            int g0 = kk * 8 + quad * 2;        // granule16 of lane's A frag
            float4 f0 = *(const float4*)(Ab + ((g0    ) ^ xsw) * 4);
            float4 f1 = *(const float4*)(Ab + ((g0 + 1) ^ xsw) * 4);
            bf16x8 a0 = __builtin_bit_cast(bf16x8, cvt8(f0, f1));
#pragma unroll
            for (int i = 0; i < 6; i++) {
                bf16x8 b = load8_bf(Bb + ((nh * 6 + i) * 2 + kk) * 512 + loff);
                acc[i] = __builtin_amdgcn_mfma_f32_16x16x32_bf16(a0, b, acc[i], 0, 0, 0);
            }
        }
        __syncthreads();   // readers of buf c done; DMA c+1 drained (vmcnt 0)
    }

    // ---- epilogue: E overlays dead A region (all chunk compute finished) ---
    // acc[i] elem (l16,quad,r) = out[rblk + strip*16 + quad*4 + r][nt*16+l16],
    // nt = nh*6 + i.  Two 32-row groups g = strip>>1, st2 = strip&1.
    {
        const int g   = strip >> 1;
        const int st2 = strip & 1;
        unsigned short* Eg = E + g * 6144;
#pragma unroll
        for (int i = 0; i < 6; i++) {
            int nt = nh * 6 + i;
#pragma unroll
            for (int r = 0; r < 4; r++) {
                unsigned short bv = f2bf(acc[i][r]);
                int off;
                if (nt < 4) {                // Q: chunk = st2*2 + part
                    off = (st2 * 2 + (nt >> 1)) * 512 +
                          (quad * 4 + r) * 32 + (nt & 1) * 16 + l16;
                } else if (nt < 8) {         // K
                    int nk = nt - 4;
                    off = 2048 + (st2 * 2 + (nk >> 1)) * 512 +
                          (quad * 4 + r) * 32 + (nk & 1) * 16 + l16;
                } else {                     // V (transposed): h-major, s minor
                    int ht = nt - 8;
                    off = 4096 + ht * 512 + l16 * 32 + st2 * 16 + quad * 4 + r;
                }
                Eg[off] = bv;
            }
        }
    }
    __syncthreads();

    // ---- copy-out: 2 groups x 12 chunks x 64 granules = 1536; 3/thread ----
#pragma unroll
    for (int c3 = 0; c3 < 3; c3++) {
        int gi  = c3 * 512 + tid;            // 0..1535
        int grp = (gi >= 768) ? 1 : 0;
        int wi  = gi - grp * 768;            // 0..767
        int ch  = wi >> 6;                   // 0..11
        int gg  = wi & 63;
        const unsigned short* src = E + grp * 6144 + ch * 512 + gg * 8;
        int t16g = t16_0 + grp * 2;
        int s32g = s32_0 + grp;
        unsigned short* dst;
        if (ch < 4) {
            dst = Qf + ((size_t)(bb * 128 + t16g + (ch >> 1)) * 2 + (ch & 1)) * 512;
        } else if (ch < 8) {
            int c2 = ch - 4;
            dst = Kf + ((size_t)(bb * 128 + t16g + (c2 >> 1)) * 2 + (c2 & 1)) * 512;
        } else {
            dst = Vf + ((size_t)(bb * 64 + s32g) * 4 + (ch - 8)) * 512;
        }
        *(u16x8*)(dst + gg * 8) = *(const u16x8*)src;
    }
}

// ---------------------------------------------------------------------------
// Kernel 2: flash attention, v8 (32 q-rows/block, 4-way KV split).
// Grid = B * T/32 = 512 blocks x 256 threads, XCD batch-affinity (b = blk&7).
// Two q-groups per block share every K/V fragment load (2x arithmetic
// intensity) and total KV tile re-read traffic halves vs v7.
// ---------------------------------------------------------------------------
#define PROW 33   // u32 per P^T row
#define OMS2 66   // u16 per O-merge row

__global__ __launch_bounds__(256) void attn(
        const unsigned short* __restrict__ Qf,
        const unsigned short* __restrict__ Kf,
        const unsigned short* __restrict__ Vf,
        float* __restrict__ out) {
    __shared__ unsigned int ps_[4 * 32 * PROW];     // 16.9 KB
    __shared__ unsigned short Om_[4 * 32 * OMS2];   // 16.9 KB
    __shared__ float mred_[4][32];
    __shared__ float lred_[4][32];

    const int tid  = threadIdx.x;
    const int wave = tid >> 6;            // KV-split index 0..3
    const int lane = tid & 63;
    const int l16  = lane & 15;
    const int quad = lane >> 4;
    const int b    = blockIdx.x & 7;      // XCD-affinity: batch = XCD
    const int qt32 = blockIdx.x >> 3;     // 0..63
    const int q0   = qt32 * 32;
    const int tdiag = qt32 >> 1;          // diagonal 64-key tile index

    const int loff = l16 * 32 + quad * 8;

    // Q as B-operand, two q-groups
    bf16x8 qf[2][2];
#pragma unroll
    for (int qg = 0; qg < 2; qg++) {
        const unsigned short* Qfb = Qf + (size_t)((b * 128 + qt32 * 2 + qg) * 2) * 512;
        qf[qg][0] = load8_bf(Qfb + loff);
        qf[qg][1] = load8_bf(Qfb + 512 + loff);
    }

    f32x4 o[8];   // [qg*4 + ht]
#pragma unroll
    for (int i = 0; i < 8; i++) o[i] = (f32x4){0.f, 0.f, 0.f, 0.f};
    float m_run[2] = {-1e30f, -1e30f}, l_run[2] = {0.f, 0.f};

    const float scale = 0.125f;  // 1/sqrt(H)
    const unsigned short* Kfb = Kf + (size_t)b * 128 * 1024;
    const unsigned short* Vfb = Vf + (size_t)b * 64 * 2048;
    unsigned int* Pw = &ps_[wave * 32 * PROW];

    for (int t = wave; t <= tdiag; t += 4) {
        // V^T A-frags: contiguous 1KB loads, issued EARLY (softmax-independent)
        bf16x8 vf[8];
#pragma unroll
        for (int ks = 0; ks < 2; ks++)
#pragma unroll
            for (int ht = 0; ht < 4; ht++)
                vf[ht * 2 + ks] = load8_bf(
                    Vfb + ((size_t)(t * 2 + ks) * 4 + ht) * 512 + loff);

        // S^T = K * Q^T for both q-groups (K frags shared)
        f32x4 s[2][4];
#pragma unroll
        for (int nt = 0; nt < 4; nt++) {
            const unsigned short* kp = Kfb + (size_t)(t * 4 + nt) * 1024;
            bf16x8 kf0 = load8_bf(kp + loff);
            bf16x8 kf1 = load8_bf(kp + 512 + loff);
#pragma unroll
            for (int qg = 0; qg < 2; qg++) {
                f32x4 z = (f32x4){0.f, 0.f, 0.f, 0.f};
                z = __builtin_amdgcn_mfma_f32_16x16x32_bf16(kf0, qf[qg][0], z, 0, 0, 0);
                z = __builtin_amdgcn_mfma_f32_16x16x32_bf16(kf1, qf[qg][1], z, 0, 0, 0);
                s[qg][nt] = z;   // S^T[s = t*64+nt*16+quad*4+r][q = q0+qg*16+l16]
            }
        }

#pragma unroll
        for (int qg = 0; qg < 2; qg++)
#pragma unroll
            for (int nt = 0; nt < 4; nt++)
#pragma unroll
                for (int r = 0; r < 4; r++) s[qg][nt][r] *= scale;

        if (t == tdiag) {   // causal: mask s > q
#pragma unroll
            for (int qg = 0; qg < 2; qg++) {
                int q = q0 + qg * 16 + l16;
#pragma unroll
                for (int nt = 0; nt < 4; nt++)
#pragma unroll
                    for (int r = 0; r < 4; r++) {
                        int key = t * 64 + nt * 16 + quad * 4 + r;
                        if (key > q) s[qg][nt][r] = -1e30f;
                    }
            }
        }

        // per-lane softmax per q-group: in-lane tree + 2 cross-quad shuffles
#pragma unroll
        for (int qg = 0; qg < 2; qg++) {
            float m0 = fmaxf(fmaxf(s[qg][0][0], s[qg][0][1]), fmaxf(s[qg][0][2], s[qg][0][3]));
            float m1 = fmaxf(fmaxf(s[qg][1][0], s[qg][1][1]), fmaxf(s[qg][1][2], s[qg][1][3]));
            float m2 = fmaxf(fmaxf(s[qg][2][0], s[qg][2][1]), fmaxf(s[qg][2][2], s[qg][2][3]));
            float m3 = fmaxf(fmaxf(s[qg][3][0], s[qg][3][1]), fmaxf(s[qg][3][2], s[qg][3][3]));
            float mx = fmaxf(fmaxf(m0, m1), fmaxf(m2, m3));
            mx = fmaxf(mx, __shfl_xor(mx, 16));
            mx = fmaxf(mx, __shfl_xor(mx, 32));
            const float m_new = fmaxf(m_run[qg], mx);
            const float alpha = __expf(m_run[qg] - m_new);
            m_run[qg] = m_new;

            float rs = 0.f;
#pragma unroll
            for (int nt = 0; nt < 4; nt++) {
#pragma unroll
                for (int i = 0; i < 2; i++) {
                    float p0 = __expf(s[qg][nt][2 * i]     - m_new);
                    float p1 = __expf(s[qg][nt][2 * i + 1] - m_new);
                    rs += p0 + p1;
                    Pw[(qg * 16 + l16) * PROW + nt * 8 + quad * 2 + i] = pack2(p0, p1);
                }
            }
            rs += __shfl_xor(rs, 16);
            rs += __shfl_xor(rs, 32);
            l_run[qg] = l_run[qg] * alpha + rs;

#pragma unroll
            for (int ht = 0; ht < 4; ht++)
#pragma unroll
                for (int r = 0; r < 4; r++) o[qg * 4 + ht][r] *= alpha;
        }

        // O^T += V^T * P^T (V frags shared across q-groups)
#pragma unroll
        for (int ks = 0; ks < 2; ks++) {
#pragma unroll
            for (int qg = 0; qg < 2; qg++) {
                bf16x8 pB = __builtin_bit_cast(bf16x8,
                    *(const u16x8*)(&Pw[(qg * 16 + l16) * PROW + ks * 16 + quad * 4]));
#pragma unroll
                for (int ht = 0; ht < 4; ht++)
                    o[qg * 4 + ht] = __builtin_amdgcn_mfma_f32_16x16x32_bf16(
                        vf[ht * 2 + ks], pB, o[qg * 4 + ht], 0, 0, 0);
            }
        }
    }

    // ---- 4-way LSE merge (O partials bf16) ----
#pragma unroll
    for (int qg = 0; qg < 2; qg++) {
#pragma unroll
        for (int ht = 0; ht < 4; ht++)
#pragma unroll
            for (int r = 0; r < 4; r++)
                Om_[(wave * 32 + qg * 16 + l16) * OMS2 + ht * 16 + quad * 4 + r] =
                    f2bf(o[qg * 4 + ht][r]);
        if (quad == 0) {
            mred_[wave][qg * 16 + l16] = m_run[qg];
            lred_[wave][qg * 16 + l16] = l_run[qg];
        }
    }
    __syncthreads();

    // finalize: thread -> (q, h); coalesced out write
    const int hcol = tid & 63;
    const int qr0  = tid >> 6;   // 0..3
#pragma unroll
    for (int qq = 0; qq < 8; qq++) {
        const int q = qr0 + qq * 4;
        float M = -1e30f;
#pragma unroll
        for (int w = 0; w < 4; w++) M = fmaxf(M, mred_[w][q]);
        float lt = 0.f, ov = 0.f;
#pragma unroll
        for (int w = 0; w < 4; w++) {
            float e = __expf(mred_[w][q] - M);
            lt += e * lred_[w][q];
            ov += e * bf2f(Om_[(w * 32 + q) * OMS2 + hcol]);
        }
        out[((size_t)b * T_ + q0 + q) * H_ + hcol] = ov / lt;
    }
}

// ---------------------------------------------------------------------------
extern "C" void kernel_launch(void* const* d_in, const int* in_sizes, int n_in,
                              void* d_out, int out_size, void* d_ws, size_t ws_size,
                              hipStream_t stream) {
    const float* x  = (const float*)d_in[0];
    const float* Wq = (const float*)d_in[1];
    const float* Wk = (const float*)d_in[2];
    const float* Wv = (const float*)d_in[3];
    float* out = (float*)d_out;

    unsigned short* Qf  = (unsigned short*)d_ws;
    unsigned short* Kf  = Qf + (size_t)B_ * T_ * H_;
    unsigned short* Vf  = Kf + (size_t)B_ * T_ * H_;
    unsigned short* Wtf = Vf + (size_t)B_ * T_ * H_;

    cast_weights<<<(192 * C_) / 256, 256, 0, stream>>>(Wq, Wk, Wv, Wtf);
    qkv_proj<<<B_ * T_ / 64, 512, 0, stream>>>(x, Wtf, Qf, Kf, Vf);
    attn<<<B_ * (T_ / 32), 256, 0, stream>>>(Qf, Kf, Vf, out);
}

// Round 8
// 141.627 us; speedup vs baseline: 1.1398x; 1.0083x over previous
//
#include <hip/hip_runtime.h>

// Problem constants (reference: B=8, T=2048, C=1024, H=64)
#define B_ 8
#define T_ 2048
#define C_ 1024
#define H_ 64

typedef __bf16 bf16x8 __attribute__((ext_vector_type(8)));
typedef float  f32x4  __attribute__((ext_vector_type(4)));
typedef unsigned short u16x8 __attribute__((ext_vector_type(8)));

// round-half-up f32 -> bf16 bits
__device__ __forceinline__ unsigned short f2bf(float f) {
    unsigned u = __builtin_bit_cast(unsigned, f);
    u += 0x8000u;
    return (unsigned short)(u >> 16);
}

__device__ __forceinline__ float bf2f(unsigned short v) {
    unsigned u = ((unsigned)v) << 16;
    return __builtin_bit_cast(float, u);
}

__device__ __forceinline__ unsigned pack2(float lo, float hi) {
    unsigned a = __builtin_bit_cast(unsigned, lo) + 0x8000u;
    unsigned b = __builtin_bit_cast(unsigned, hi) + 0x8000u;
    return (a >> 16) | (b & 0xffff0000u);
}

union U8 { unsigned u32[4]; u16x8 v; };

__device__ __forceinline__ u16x8 cvt8(float4 f0, float4 f1) {
    U8 r;
    r.u32[0] = pack2(f0.x, f0.y);
    r.u32[1] = pack2(f0.z, f0.w);
    r.u32[2] = pack2(f1.x, f1.y);
    r.u32[3] = pack2(f1.z, f1.w);
    return r.v;
}

__device__ __forceinline__ bf16x8 load8_bf(const unsigned short* p) {
    return __builtin_bit_cast(bf16x8, *(const u16x8*)p);
}

// Async global->LDS, 16B per lane, no destination VGPRs (vmcnt-counted).
// Dest = wave-uniform base + lane*16 (linear); source addr is per-lane.
__device__ __forceinline__ void gload_lds16(const float* g, float* l) {
    __builtin_amdgcn_global_load_lds(
        (const __attribute__((address_space(1))) unsigned int*)g,
        (__attribute__((address_space(3))) unsigned int*)l, 16, 0, 0);
}

// Fragment-major layouts (contiguous 1KB-per-wave loads):
//   Qf/Kf[b][t16][part][l16*32 + quad*8 + j]   (t16 = seq/16, part = h/32)
//   Vf[b][s32][ht][l16*32 + quad*8 + j]        (s32 = seq/32, ht = h/16)
//   Wtf[nt][kk][l16*32 + quad*8 + j]           (nt = ncol/16 of 192, kk = c/32)

// ---------------------------------------------------------------------------
// Kernel 0: pack Wq,Wk,Wv (fp32 [C][H]) straight into fragment-major Wtf.
// ---------------------------------------------------------------------------
__global__ void cast_weights(const float* __restrict__ Wq,
                             const float* __restrict__ Wk,
                             const float* __restrict__ Wv,
                             unsigned short* __restrict__ Wtf) {
    int idx = blockIdx.x * blockDim.x + threadIdx.x;   // 0 .. 192*1024-1
    int n   = idx % 192;        // global out col
    int c   = idx / 192;        // k index
    int w   = n >> 6;
    int h   = n & 63;
    const float* W = (w == 0) ? Wq : (w == 1) ? Wk : Wv;
    int nt = n >> 4, l16 = n & 15;
    int kk = c >> 5, quad = (c >> 3) & 3, j = c & 7;
    Wtf[(size_t)(nt * 32 + kk) * 512 + l16 * 32 + quad * 8 + j] =
        f2bf(W[(size_t)c * H_ + h]);
}

// ---------------------------------------------------------------------------
// Kernel 1: fused QKV projection, v15 = v14 + counted-vmcnt pipeline (T4).
// v14 (verified, 42us) exposed the mechanism exactly: per chunk only ~465cy
// of compute but 6300cy wall — __syncthreads' implicit vmcnt(0) drains the
// whole staging DMA every chunk, 1-deep prefetch, 1 block/CU -> ~93% stall.
// v15 keeps v14's verified stage/compute/epilogue bodies and changes ONLY
// the sync structure:
//   - 4 LDS buffers (4 x 40KB = 160KB, the HK/AITER budget)
//   - prologue stages chunks 0..2 (15 issues/wave in flight)
//   - per chunk: s_waitcnt vmcnt(10) [chunk c retired, c+1/c+2 flying]
//     -> raw s_barrier -> sched_barrier(0) -> stage(c+3) -> compute(c)
//   - tail: vmcnt(5) at c=14, vmcnt(0) at c=15. Never vmcnt(0) mid-loop.
// Safety: issue counts are wave-uniform (5/chunk), so own-wave vmcnt + the
// barrier ==> chunk c globally visible. stage(c+3) writes buf (c-1)&3 whose
// readers' ds_reads retired before they reached this barrier (data in VGPRs;
// lgkmcnt waits precede the MFMAs that precede the barrier). One barrier
// per chunk. E epilogue overlays buf0 (dead after chunk 12; all DMA drained
// by c=15's vmcnt(0)).
// ---------------------------------------------------------------------------
#define NCH 16   // K chunks (1024 / 64)

__global__ __launch_bounds__(512, 2) void qkv_proj(
        const float* __restrict__ x,
        const unsigned short* __restrict__ Wtf,
        unsigned short* __restrict__ Qf,
        unsigned short* __restrict__ Kf,
        unsigned short* __restrict__ Vf) {
    __shared__ __attribute__((aligned(16))) char smem[163840];  // 160 KB
    // A buffers: 4 x 16 KB at [0, 64K); B buffers: 4 x 24 KB at [64K, 160K)
    unsigned short* E = (unsigned short*)smem;                  // 24 KB overlay

    const int tid   = threadIdx.x;
    const int w     = tid >> 6;        // wave 0..7
    const int strip = w & 3;           // m-strip (16 rows)
    const int nh    = w >> 2;          // n-half (6 n-tiles = 96 cols)
    const int lane  = tid & 63;
    const int l16   = lane & 15;
    const int quad  = lane >> 4;
    const size_t rblk = (size_t)blockIdx.x * 64;
    const int bb    = (int)(rblk >> 11);
    const int tloc0 = (int)(rblk & (T_ - 1));
    const int t16_0 = tloc0 >> 4;
    const int s32_0 = tloc0 >> 5;
    const int loff  = l16 * 32 + quad * 8;
    const int xsw   = l16 & 7;

    // ---- stage chunk c into buffer c&3: 40 x 1KB issues, 5 per wave ----
    auto stage = [&](int c) {
        float* Ab          = (float*)(smem + (c & 3) * 16384);
        char*  Bb          = smem + 65536 + (c & 3) * 24576;
#pragma unroll
        for (int q = 0; q < 5; q++) {
            int j = w * 5 + q;                 // 0..39
            if (j < 16) {                      // A: 64x64 fp32, swz source
                int row  = j * 4 + (lane >> 4);    // 0..63 (block-local)
                int slot = lane & 15;              // 16B slot within row
                int g    = slot ^ (row & 7);       // global granule16
                gload_lds16(x + (rblk + row) * C_ + c * 64 + g * 4,
                            Ab + j * 256);
            } else {                           // B: 24 x 1KB frag blocks
                int jb = j - 16;               // 0..23
                int nt = jb >> 1, kkl = jb & 1;
                gload_lds16(
                    (const float*)(Wtf + ((size_t)nt * 32 + c * 2 + kkl) * 512
                                   + (size_t)lane * 8),
                    (float*)(Bb + jb * 1024));
            }
        }
    };

    f32x4 acc[6];
#pragma unroll
    for (int i = 0; i < 6; i++) acc[i] = (f32x4){0.f, 0.f, 0.f, 0.f};

    stage(0); stage(1); stage(2);          // 15 issues/wave in flight

    for (int c = 0; c < NCH; c++) {
        // counted wait: chunk c retired; newer chunks stay in flight
        if (c < NCH - 2)       asm volatile("s_waitcnt vmcnt(10)" ::: "memory");
        else if (c == NCH - 2) asm volatile("s_waitcnt vmcnt(5)"  ::: "memory");
        else                   asm volatile("s_waitcnt vmcnt(0)"  ::: "memory");
        __builtin_amdgcn_s_barrier();
        __builtin_amdgcn_sched_barrier(0);

        if (c + 3 < NCH) stage(c + 3);     // writes buf (c-1)&3 (dead)

        const float* Ab = (const float*)(smem + (c & 3) * 16384)
                          + (strip * 16 + l16) * 64;
        const unsigned short* Bb =
            (const unsigned short*)(smem + 65536 + (c & 3) * 24576);
#pragma unroll
        for (int kk = 0; kk < 2; kk++) {
            int g0 = kk * 8 + quad * 2;        // granule16 of lane's A frag
            float4 f0 = *(const float4*)(Ab + ((g0    ) ^ xsw) * 4);
            float4 f1 = *(const float4*)(Ab + ((g0 + 1) ^ xsw) * 4);
            bf16x8 a0 = __builtin_bit_cast(bf16x8, cvt8(f0, f1));
#pragma unroll
            for (int i = 0; i < 6; i++) {
                bf16x8 b = load8_bf(Bb + ((nh * 6 + i) * 2 + kk) * 512 + loff);
                acc[i] = __builtin_amdgcn_mfma_f32_16x16x32_bf16(a0, b, acc[i], 0, 0, 0);
            }
        }
    }

    // ---- epilogue: E overlays buf0 (dead; all DMA drained at c=15) ----
    // acc[i] elem (l16,quad,r) = out[rblk + strip*16 + quad*4 + r][nt*16+l16],
    // nt = nh*6 + i.  Two 32-row groups g = strip>>1, st2 = strip&1.
    {
        const int g   = strip >> 1;
        const int st2 = strip & 1;
        unsigned short* Eg = E + g * 6144;
#pragma unroll
        for (int i = 0; i < 6; i++) {
            int nt = nh * 6 + i;
#pragma unroll
            for (int r = 0; r < 4; r++) {
                unsigned short bv = f2bf(acc[i][r]);
                int off;
                if (nt < 4) {                // Q: chunk = st2*2 + part
                    off = (st2 * 2 + (nt >> 1)) * 512 +
                          (quad * 4 + r) * 32 + (nt & 1) * 16 + l16;
                } else if (nt < 8) {         // K
                    int nk = nt - 4;
                    off = 2048 + (st2 * 2 + (nk >> 1)) * 512 +
                          (quad * 4 + r) * 32 + (nk & 1) * 16 + l16;
                } else {                     // V (transposed): h-major, s minor
                    int ht = nt - 8;
                    off = 4096 + ht * 512 + l16 * 32 + st2 * 16 + quad * 4 + r;
                }
                Eg[off] = bv;
            }
        }
    }
    __syncthreads();

    // ---- copy-out: 2 groups x 12 chunks x 64 granules = 1536; 3/thread ----
#pragma unroll
    for (int c3 = 0; c3 < 3; c3++) {
        int gi  = c3 * 512 + tid;            // 0..1535
        int grp = (gi >= 768) ? 1 : 0;
        int wi  = gi - grp * 768;            // 0..767
        int ch  = wi >> 6;                   // 0..11
        int gg  = wi & 63;
        const unsigned short* src = E + grp * 6144 + ch * 512 + gg * 8;
        int t16g = t16_0 + grp * 2;
        int s32g = s32_0 + grp;
        unsigned short* dst;
        if (ch < 4) {
            dst = Qf + ((size_t)(bb * 128 + t16g + (ch >> 1)) * 2 + (ch & 1)) * 512;
        } else if (ch < 8) {
            int c2 = ch - 4;
            dst = Kf + ((size_t)(bb * 128 + t16g + (c2 >> 1)) * 2 + (c2 & 1)) * 512;
        } else {
            dst = Vf + ((size_t)(bb * 64 + s32g) * 4 + (ch - 8)) * 512;
        }
        *(u16x8*)(dst + gg * 8) = *(const u16x8*)src;
    }
}

// ---------------------------------------------------------------------------
// Kernel 2: flash attention, v8 (32 q-rows/block, 4-way KV split).
// Grid = B * T/32 = 512 blocks x 256 threads, XCD batch-affinity (b = blk&7).
// Two q-groups per block share every K/V fragment load (2x arithmetic
// intensity) and total KV tile re-read traffic halves vs v7.
// ---------------------------------------------------------------------------
#define PROW 33   // u32 per P^T row
#define OMS2 66   // u16 per O-merge row

__global__ __launch_bounds__(256) void attn(
        const unsigned short* __restrict__ Qf,
        const unsigned short* __restrict__ Kf,
        const unsigned short* __restrict__ Vf,
        float* __restrict__ out) {
    __shared__ unsigned int ps_[4 * 32 * PROW];     // 16.9 KB
    __shared__ unsigned short Om_[4 * 32 * OMS2];   // 16.9 KB
    __shared__ float mred_[4][32];
    __shared__ float lred_[4][32];

    const int tid  = threadIdx.x;
    const int wave = tid >> 6;            // KV-split index 0..3
    const int lane = tid & 63;
    const int l16  = lane & 15;
    const int quad = lane >> 4;
    const int b    = blockIdx.x & 7;      // XCD-affinity: batch = XCD
    const int qt32 = blockIdx.x >> 3;     // 0..63
    const int q0   = qt32 * 32;
    const int tdiag = qt32 >> 1;          // diagonal 64-key tile index

    const int loff = l16 * 32 + quad * 8;

    // Q as B-operand, two q-groups
    bf16x8 qf[2][2];
#pragma unroll
    for (int qg = 0; qg < 2; qg++) {
        const unsigned short* Qfb = Qf + (size_t)((b * 128 + qt32 * 2 + qg) * 2) * 512;
        qf[qg][0] = load8_bf(Qfb + loff);
        qf[qg][1] = load8_bf(Qfb + 512 + loff);
    }

    f32x4 o[8];   // [qg*4 + ht]
#pragma unroll
    for (int i = 0; i < 8; i++) o[i] = (f32x4){0.f, 0.f, 0.f, 0.f};
    float m_run[2] = {-1e30f, -1e30f}, l_run[2] = {0.f, 0.f};

    const float scale = 0.125f;  // 1/sqrt(H)
    const unsigned short* Kfb = Kf + (size_t)b * 128 * 1024;
    const unsigned short* Vfb = Vf + (size_t)b * 64 * 2048;
    unsigned int* Pw = &ps_[wave * 32 * PROW];

    for (int t = wave; t <= tdiag; t += 4) {
        // V^T A-frags: contiguous 1KB loads, issued EARLY (softmax-independent)
        bf16x8 vf[8];
#pragma unroll
        for (int ks = 0; ks < 2; ks++)
#pragma unroll
            for (int ht = 0; ht < 4; ht++)
                vf[ht * 2 + ks] = load8_bf(
                    Vfb + ((size_t)(t * 2 + ks) * 4 + ht) * 512 + loff);

        // S^T = K * Q^T for both q-groups (K frags shared)
        f32x4 s[2][4];
#pragma unroll
        for (int nt = 0; nt < 4; nt++) {
            const unsigned short* kp = Kfb + (size_t)(t * 4 + nt) * 1024;
            bf16x8 kf0 = load8_bf(kp + loff);
            bf16x8 kf1 = load8_bf(kp + 512 + loff);
#pragma unroll
            for (int qg = 0; qg < 2; qg++) {
                f32x4 z = (f32x4){0.f, 0.f, 0.f, 0.f};
                z = __builtin_amdgcn_mfma_f32_16x16x32_bf16(kf0, qf[qg][0], z, 0, 0, 0);
                z = __builtin_amdgcn_mfma_f32_16x16x32_bf16(kf1, qf[qg][1], z, 0, 0, 0);
                s[qg][nt] = z;   // S^T[s = t*64+nt*16+quad*4+r][q = q0+qg*16+l16]
            }
        }

#pragma unroll
        for (int qg = 0; qg < 2; qg++)
#pragma unroll
            for (int nt = 0; nt < 4; nt++)
#pragma unroll
                for (int r = 0; r < 4; r++) s[qg][nt][r] *= scale;

        if (t == tdiag) {   // causal: mask s > q
#pragma unroll
            for (int qg = 0; qg < 2; qg++) {
                int q = q0 + qg * 16 + l16;
#pragma unroll
                for (int nt = 0; nt < 4; nt++)
#pragma unroll
                    for (int r = 0; r < 4; r++) {
                        int key = t * 64 + nt * 16 + quad * 4 + r;
                        if (key > q) s[qg][nt][r] = -1e30f;
                    }
            }
        }

        // per-lane softmax per q-group: in-lane tree + 2 cross-quad shuffles
#pragma unroll
        for (int qg = 0; qg < 2; qg++) {
            float m0 = fmaxf(fmaxf(s[qg][0][0], s[qg][0][1]), fmaxf(s[qg][0][2], s[qg][0][3]));
            float m1 = fmaxf(fmaxf(s[qg][1][0], s[qg][1][1]), fmaxf(s[qg][1][2], s[qg][1][3]));
            float m2 = fmaxf(fmaxf(s[qg][2][0], s[qg][2][1]), fmaxf(s[qg][2][2], s[qg][2][3]));
            float m3 = fmaxf(fmaxf(s[qg][3][0], s[qg][3][1]), fmaxf(s[qg][3][2], s[qg][3][3]));
            float mx = fmaxf(fmaxf(m0, m1), fmaxf(m2, m3));
            mx = fmaxf(mx, __shfl_xor(mx, 16));
            mx = fmaxf(mx, __shfl_xor(mx, 32));
            const float m_new = fmaxf(m_run[qg], mx);
            const float alpha = __expf(m_run[qg] - m_new);
            m_run[qg] = m_new;

            float rs = 0.f;
#pragma unroll
            for (int nt = 0; nt < 4; nt++) {
#pragma unroll
                for (int i = 0; i < 2; i++) {
                    float p0 = __expf(s[qg][nt][2 * i]     - m_new);
                    float p1 = __expf(s[qg][nt][2 * i + 1] - m_new);
                    rs += p0 + p1;
                    Pw[(qg * 16 + l16) * PROW + nt * 8 + quad * 2 + i] = pack2(p0, p1);
                }
            }
            rs += __shfl_xor(rs, 16);
            rs += __shfl_xor(rs, 32);
            l_run[qg] = l_run[qg] * alpha + rs;

#pragma unroll
            for (int ht = 0; ht < 4; ht++)
#pragma unroll
                for (int r = 0; r < 4; r++) o[qg * 4 + ht][r] *= alpha;
        }

        // O^T += V^T * P^T (V frags shared across q-groups)
#pragma unroll
        for (int ks = 0; ks < 2; ks++) {
#pragma unroll
            for (int qg = 0; qg < 2; qg++) {
                bf16x8 pB = __builtin_bit_cast(bf16x8,
                    *(const u16x8*)(&Pw[(qg * 16 + l16) * PROW + ks * 16 + quad * 4]));
#pragma unroll
                for (int ht = 0; ht < 4; ht++)
                    o[qg * 4 + ht] = __builtin_amdgcn_mfma_f32_16x16x32_bf16(
                        vf[ht * 2 + ks], pB, o[qg * 4 + ht], 0, 0, 0);
            }
        }
    }

    // ---- 4-way LSE merge (O partials bf16) ----
#pragma unroll
    for (int qg = 0; qg < 2; qg++) {
#pragma unroll
        for (int ht = 0; ht < 4; ht++)
#pragma unroll
            for (int r = 0; r < 4; r++)
                Om_[(wave * 32 + qg * 16 + l16) * OMS2 + ht * 16 + quad * 4 + r] =
                    f2bf(o[qg * 4 + ht][r]);
        if (quad == 0) {
            mred_[wave][qg * 16 + l16] = m_run[qg];
            lred_[wave][qg * 16 + l16] = l_run[qg];
        }
    }
    __syncthreads();

    // finalize: thread -> (q, h); coalesced out write
    const int hcol = tid & 63;
    const int qr0  = tid >> 6;   // 0..3
#pragma unroll
    for (int qq = 0; qq < 8; qq++) {
        const int q = qr0 + qq * 4;
        float M = -1e30f;
#pragma unroll
        for (int w = 0; w < 4; w++) M = fmaxf(M, mred_[w][q]);
        float lt = 0.f, ov = 0.f;
#pragma unroll
        for (int w = 0; w < 4; w++) {
            float e = __expf(mred_[w][q] - M);
            lt += e * lred_[w][q];
            ov += e * bf2f(Om_[(w * 32 + q) * OMS2 + hcol]);
        }
        out[((size_t)b * T_ + q0 + q) * H_ + hcol] = ov / lt;
    }
}

// ---------------------------------------------------------------------------
extern "C" void kernel_launch(void* const* d_in, const int* in_sizes, int n_in,
                              void* d_out, int out_size, void* d_ws, size_t ws_size,
                              hipStream_t stream) {
    const float* x  = (const float*)d_in[0];
    const float* Wq = (const float*)d_in[1];
    const float* Wk = (const float*)d_in[2];
    const float* Wv = (const float*)d_in[3];
    float* out = (float*)d_out;

    unsigned short* Qf  = (unsigned short*)d_ws;
    unsigned short* Kf  = Qf + (size_t)B_ * T_ * H_;
    unsigned short* Vf  = Kf + (size_t)B_ * T_ * H_;
    unsigned short* Wtf = Vf + (size_t)B_ * T_ * H_;

    cast_weights<<<(192 * C_) / 256, 256, 0, stream>>>(Wq, Wk, Wv, Wtf);
    qkv_proj<<<B_ * T_ / 64, 512, 0, stream>>>(x, Wtf, Qf, Kf, Vf);
    attn<<<B_ * (T_ / 32), 256, 0, stream>>>(Qf, Kf, Vf, out);
}

// Round 9
// 141.146 us; speedup vs baseline: 1.1437x; 1.0034x over previous
//
#include <hip/hip_runtime.h>

// Problem constants (reference: B=8, T=2048, C=1024, H=64)
#define B_ 8
#define T_ 2048
#define C_ 1024
#define H_ 64

typedef __bf16 bf16x8 __attribute__((ext_vector_type(8)));
typedef float  f32x4  __attribute__((ext_vector_type(4)));
typedef unsigned short u16x8 __attribute__((ext_vector_type(8)));

// round-half-up f32 -> bf16 bits
__device__ __forceinline__ unsigned short f2bf(float f) {
    unsigned u = __builtin_bit_cast(unsigned, f);
    u += 0x8000u;
    return (unsigned short)(u >> 16);
}

__device__ __forceinline__ float bf2f(unsigned short v) {
    unsigned u = ((unsigned)v) << 16;
    return __builtin_bit_cast(float, u);
}

__device__ __forceinline__ unsigned pack2(float lo, float hi) {
    unsigned a = __builtin_bit_cast(unsigned, lo) + 0x8000u;
    unsigned b = __builtin_bit_cast(unsigned, hi) + 0x8000u;
    return (a >> 16) | (b & 0xffff0000u);
}

union U8 { unsigned u32[4]; u16x8 v; };

__device__ __forceinline__ u16x8 cvt8(float4 f0, float4 f1) {
    U8 r;
    r.u32[0] = pack2(f0.x, f0.y);
    r.u32[1] = pack2(f0.z, f0.w);
    r.u32[2] = pack2(f1.x, f1.y);
    r.u32[3] = pack2(f1.z, f1.w);
    return r.v;
}

__device__ __forceinline__ bf16x8 load8_bf(const unsigned short* p) {
    return __builtin_bit_cast(bf16x8, *(const u16x8*)p);
}

// Async global->LDS, 16B per lane, no destination VGPRs (vmcnt-counted).
// Dest = wave-uniform base + lane*16 (linear); source addr is per-lane.
__device__ __forceinline__ void gload_lds16(const float* g, float* l) {
    __builtin_amdgcn_global_load_lds(
        (const __attribute__((address_space(1))) unsigned int*)g,
        (__attribute__((address_space(3))) unsigned int*)l, 16, 0, 0);
}

// Fragment-major layouts (contiguous 1KB-per-wave loads):
//   Qf/Kf[b][t16][part][l16*32 + quad*8 + j]   (t16 = seq/16, part = h/32)
//   Vf[b][s32][ht][l16*32 + quad*8 + j]        (s32 = seq/32, ht = h/16)
//   Wtf[nt][kk][l16*32 + quad*8 + j]           (nt = ncol/16 of 192, kk = c/32)

// ---------------------------------------------------------------------------
// Kernel 0: pack Wq,Wk,Wv (fp32 [C][H]) straight into fragment-major Wtf.
// ---------------------------------------------------------------------------
__global__ void cast_weights(const float* __restrict__ Wq,
                             const float* __restrict__ Wk,
                             const float* __restrict__ Wv,
                             unsigned short* __restrict__ Wtf) {
    int idx = blockIdx.x * blockDim.x + threadIdx.x;   // 0 .. 192*1024-1
    int n   = idx % 192;        // global out col
    int c   = idx / 192;        // k index
    int w   = n >> 6;
    int h   = n & 63;
    const float* W = (w == 0) ? Wq : (w == 1) ? Wk : Wv;
    int nt = n >> 4, l16 = n & 15;
    int kk = c >> 5, quad = (c >> 3) & 3, j = c & 7;
    Wtf[(size_t)(nt * 32 + kk) * 512 + l16 * 32 + quad * 8 + j] =
        f2bf(W[(size_t)c * H_ + h]);
}

// ---------------------------------------------------------------------------
// Kernel 1: fused QKV projection, v16 = v15 + B bank-conflict involution.
// v15 (counted-vmcnt 4-buffer pipeline, verified) removed the per-chunk
// vmcnt(0) drain but stayed ~40us. Residual arithmetic: 128 ds_read_b128
// per chunk per CU, and the B-read offset l16*32+quad*8 (u16) = 64B lane
// stride = word 16*l16 -> each quarter-wave alternates between bank groups
// {0-3} and {16-19} only: 8-WAY CONFLICT on all 12 B-reads/wave/chunk
// (SQ_LDS_BANK_CONFLICT 2.39M). A-reads were swizzle-protected; B was not.
// v16 applies rule-#21's both-sides involution to B's 64 16B slots:
//   p(s) = s ^ (s>>3)   (bits 0-2 ^= bits 3-5; self-inverse)
//   - stage: lane fetches SOURCE granule p(lane), LDS dest linear
//   - read:  slot p(l16*4+quad) -> quarter-wave covers all 8 bank groups
//     twice each = 2-way = free (m136).
// Everything else identical to v15 (pipeline, barriers, epilogue).
// ---------------------------------------------------------------------------
#define NCH 16   // K chunks (1024 / 64)

__global__ __launch_bounds__(512, 2) void qkv_proj(
        const float* __restrict__ x,
        const unsigned short* __restrict__ Wtf,
        unsigned short* __restrict__ Qf,
        unsigned short* __restrict__ Kf,
        unsigned short* __restrict__ Vf) {
    __shared__ __attribute__((aligned(16))) char smem[163840];  // 160 KB
    // A buffers: 4 x 16 KB at [0, 64K); B buffers: 4 x 24 KB at [64K, 160K)
    unsigned short* E = (unsigned short*)smem;                  // 24 KB overlay

    const int tid   = threadIdx.x;
    const int w     = tid >> 6;        // wave 0..7
    const int strip = w & 3;           // m-strip (16 rows)
    const int nh    = w >> 2;          // n-half (6 n-tiles = 96 cols)
    const int lane  = tid & 63;
    const int l16   = lane & 15;
    const int quad  = lane >> 4;
    const size_t rblk = (size_t)blockIdx.x * 64;
    const int bb    = (int)(rblk >> 11);
    const int tloc0 = (int)(rblk & (T_ - 1));
    const int t16_0 = tloc0 >> 4;
    const int s32_0 = tloc0 >> 5;
    const int xsw   = l16 & 7;
    // B slot involution: lane's fragment granule s=l16*4+quad lives at p(s);
    // (s>>3) == l16>>1 for s = 4*l16+quad.
    const int bs8   = (((l16 * 4 + quad) ^ (l16 >> 1)) * 8);   // u16 offset

    // ---- stage chunk c into buffer c&3: 40 x 1KB issues, 5 per wave ----
    auto stage = [&](int c) {
        float* Ab          = (float*)(smem + (c & 3) * 16384);
        char*  Bb          = smem + 65536 + (c & 3) * 24576;
#pragma unroll
        for (int q = 0; q < 5; q++) {
            int j = w * 5 + q;                 // 0..39
            if (j < 16) {                      // A: 64x64 fp32, swz source
                int row  = j * 4 + (lane >> 4);    // 0..63 (block-local)
                int slot = lane & 15;              // 16B slot within row
                int g    = slot ^ (row & 7);       // global granule16
                gload_lds16(x + (rblk + row) * C_ + c * 64 + g * 4,
                            Ab + j * 256);
            } else {                           // B: 24 x 1KB frag blocks
                int jb = j - 16;               // 0..23
                int nt = jb >> 1, kkl = jb & 1;
                int sl = lane ^ (lane >> 3);   // source granule p(lane)
                gload_lds16(
                    (const float*)(Wtf + ((size_t)nt * 32 + c * 2 + kkl) * 512
                                   + (size_t)sl * 8),
                    (float*)(Bb + jb * 1024));
            }
        }
    };

    f32x4 acc[6];
#pragma unroll
    for (int i = 0; i < 6; i++) acc[i] = (f32x4){0.f, 0.f, 0.f, 0.f};

    stage(0); stage(1); stage(2);          // 15 issues/wave in flight

    for (int c = 0; c < NCH; c++) {
        // counted wait: chunk c retired; newer chunks stay in flight
        if (c < NCH - 2)       asm volatile("s_waitcnt vmcnt(10)" ::: "memory");
        else if (c == NCH - 2) asm volatile("s_waitcnt vmcnt(5)"  ::: "memory");
        else                   asm volatile("s_waitcnt vmcnt(0)"  ::: "memory");
        __builtin_amdgcn_s_barrier();
        __builtin_amdgcn_sched_barrier(0);

        if (c + 3 < NCH) stage(c + 3);     // writes buf (c-1)&3 (dead)

        const float* Ab = (const float*)(smem + (c & 3) * 16384)
                          + (strip * 16 + l16) * 64;
        const unsigned short* Bb =
            (const unsigned short*)(smem + 65536 + (c & 3) * 24576);
#pragma unroll
        for (int kk = 0; kk < 2; kk++) {
            int g0 = kk * 8 + quad * 2;        // granule16 of lane's A frag
            float4 f0 = *(const float4*)(Ab + ((g0    ) ^ xsw) * 4);
            float4 f1 = *(const float4*)(Ab + ((g0 + 1) ^ xsw) * 4);
            bf16x8 a0 = __builtin_bit_cast(bf16x8, cvt8(f0, f1));
#pragma unroll
            for (int i = 0; i < 6; i++) {
                bf16x8 b = load8_bf(Bb + ((nh * 6 + i) * 2 + kk) * 512 + bs8);
                acc[i] = __builtin_amdgcn_mfma_f32_16x16x32_bf16(a0, b, acc[i], 0, 0, 0);
            }
        }
    }

    // ---- epilogue: E overlays buf0 (dead; all DMA drained at c=15) ----
    // acc[i] elem (l16,quad,r) = out[rblk + strip*16 + quad*4 + r][nt*16+l16],
    // nt = nh*6 + i.  Two 32-row groups g = strip>>1, st2 = strip&1.
    {
        const int g   = strip >> 1;
        const int st2 = strip & 1;
        unsigned short* Eg = E + g * 6144;
#pragma unroll
        for (int i = 0; i < 6; i++) {
            int nt = nh * 6 + i;
#pragma unroll
            for (int r = 0; r < 4; r++) {
                unsigned short bv = f2bf(acc[i][r]);
                int off;
                if (nt < 4) {                // Q: chunk = st2*2 + part
                    off = (st2 * 2 + (nt >> 1)) * 512 +
                          (quad * 4 + r) * 32 + (nt & 1) * 16 + l16;
                } else if (nt < 8) {         // K
                    int nk = nt - 4;
                    off = 2048 + (st2 * 2 + (nk >> 1)) * 512 +
                          (quad * 4 + r) * 32 + (nk & 1) * 16 + l16;
                } else {                     // V (transposed): h-major, s minor
                    int ht = nt - 8;
                    off = 4096 + ht * 512 + l16 * 32 + st2 * 16 + quad * 4 + r;
                }
                Eg[off] = bv;
            }
        }
    }
    __syncthreads();

    // ---- copy-out: 2 groups x 12 chunks x 64 granules = 1536; 3/thread ----
#pragma unroll
    for (int c3 = 0; c3 < 3; c3++) {
        int gi  = c3 * 512 + tid;            // 0..1535
        int grp = (gi >= 768) ? 1 : 0;
        int wi  = gi - grp * 768;            // 0..767
        int ch  = wi >> 6;                   // 0..11
        int gg  = wi & 63;
        const unsigned short* src = E + grp * 6144 + ch * 512 + gg * 8;
        int t16g = t16_0 + grp * 2;
        int s32g = s32_0 + grp;
        unsigned short* dst;
        if (ch < 4) {
            dst = Qf + ((size_t)(bb * 128 + t16g + (ch >> 1)) * 2 + (ch & 1)) * 512;
        } else if (ch < 8) {
            int c2 = ch - 4;
            dst = Kf + ((size_t)(bb * 128 + t16g + (c2 >> 1)) * 2 + (c2 & 1)) * 512;
        } else {
            dst = Vf + ((size_t)(bb * 64 + s32g) * 4 + (ch - 8)) * 512;
        }
        *(u16x8*)(dst + gg * 8) = *(const u16x8*)src;
    }
}

// ---------------------------------------------------------------------------
// Kernel 2: flash attention, v8 (32 q-rows/block, 4-way KV split).
// Grid = B * T/32 = 512 blocks x 256 threads, XCD batch-affinity (b = blk&7).
// Two q-groups per block share every K/V fragment load (2x arithmetic
// intensity) and total KV tile re-read traffic halves vs v7.
// ---------------------------------------------------------------------------
#define PROW 33   // u32 per P^T row
#define OMS2 66   // u16 per O-merge row

__global__ __launch_bounds__(256) void attn(
        const unsigned short* __restrict__ Qf,
        const unsigned short* __restrict__ Kf,
        const unsigned short* __restrict__ Vf,
        float* __restrict__ out) {
    __shared__ unsigned int ps_[4 * 32 * PROW];     // 16.9 KB
    __shared__ unsigned short Om_[4 * 32 * OMS2];   // 16.9 KB
    __shared__ float mred_[4][32];
    __shared__ float lred_[4][32];

    const int tid  = threadIdx.x;
    const int wave = tid >> 6;            // KV-split index 0..3
    const int lane = tid & 63;
    const int l16  = lane & 15;
    const int quad = lane >> 4;
    const int b    = blockIdx.x & 7;      // XCD-affinity: batch = XCD
    const int qt32 = blockIdx.x >> 3;     // 0..63
    const int q0   = qt32 * 32;
    const int tdiag = qt32 >> 1;          // diagonal 64-key tile index

    const int loff = l16 * 32 + quad * 8;

    // Q as B-operand, two q-groups
    bf16x8 qf[2][2];
#pragma unroll
    for (int qg = 0; qg < 2; qg++) {
        const unsigned short* Qfb = Qf + (size_t)((b * 128 + qt32 * 2 + qg) * 2) * 512;
        qf[qg][0] = load8_bf(Qfb + loff);
        qf[qg][1] = load8_bf(Qfb + 512 + loff);
    }

    f32x4 o[8];   // [qg*4 + ht]
#pragma unroll
    for (int i = 0; i < 8; i++) o[i] = (f32x4){0.f, 0.f, 0.f, 0.f};
    float m_run[2] = {-1e30f, -1e30f}, l_run[2] = {0.f, 0.f};

    const float scale = 0.125f;  // 1/sqrt(H)
    const unsigned short* Kfb = Kf + (size_t)b * 128 * 1024;
    const unsigned short* Vfb = Vf + (size_t)b * 64 * 2048;
    unsigned int* Pw = &ps_[wave * 32 * PROW];

    for (int t = wave; t <= tdiag; t += 4) {
        // V^T A-frags: contiguous 1KB loads, issued EARLY (softmax-independent)
        bf16x8 vf[8];
#pragma unroll
        for (int ks = 0; ks < 2; ks++)
#pragma unroll
            for (int ht = 0; ht < 4; ht++)
                vf[ht * 2 + ks] = load8_bf(
                    Vfb + ((size_t)(t * 2 + ks) * 4 + ht) * 512 + loff);

        // S^T = K * Q^T for both q-groups (K frags shared)
        f32x4 s[2][4];
#pragma unroll
        for (int nt = 0; nt < 4; nt++) {
            const unsigned short* kp = Kfb + (size_t)(t * 4 + nt) * 1024;
            bf16x8 kf0 = load8_bf(kp + loff);
            bf16x8 kf1 = load8_bf(kp + 512 + loff);
#pragma unroll
            for (int qg = 0; qg < 2; qg++) {
                f32x4 z = (f32x4){0.f, 0.f, 0.f, 0.f};
                z = __builtin_amdgcn_mfma_f32_16x16x32_bf16(kf0, qf[qg][0], z, 0, 0, 0);
                z = __builtin_amdgcn_mfma_f32_16x16x32_bf16(kf1, qf[qg][1], z, 0, 0, 0);
                s[qg][nt] = z;   // S^T[s = t*64+nt*16+quad*4+r][q = q0+qg*16+l16]
            }
        }

#pragma unroll
        for (int qg = 0; qg < 2; qg++)
#pragma unroll
            for (int nt = 0; nt < 4; nt++)
#pragma unroll
                for (int r = 0; r < 4; r++) s[qg][nt][r] *= scale;

        if (t == tdiag) {   // causal: mask s > q
#pragma unroll
            for (int qg = 0; qg < 2; qg++) {
                int q = q0 + qg * 16 + l16;
#pragma unroll
                for (int nt = 0; nt < 4; nt++)
#pragma unroll
                    for (int r = 0; r < 4; r++) {
                        int key = t * 64 + nt * 16 + quad * 4 + r;
                        if (key > q) s[qg][nt][r] = -1e30f;
                    }
            }
        }

        // per-lane softmax per q-group: in-lane tree + 2 cross-quad shuffles
#pragma unroll
        for (int qg = 0; qg < 2; qg++) {
            float m0 = fmaxf(fmaxf(s[qg][0][0], s[qg][0][1]), fmaxf(s[qg][0][2], s[qg][0][3]));
            float m1 = fmaxf(fmaxf(s[qg][1][0], s[qg][1][1]), fmaxf(s[qg][1][2], s[qg][1][3]));
            float m2 = fmaxf(fmaxf(s[qg][2][0], s[qg][2][1]), fmaxf(s[qg][2][2], s[qg][2][3]));
            float m3 = fmaxf(fmaxf(s[qg][3][0], s[qg][3][1]), fmaxf(s[qg][3][2], s[qg][3][3]));
            float mx = fmaxf(fmaxf(m0, m1), fmaxf(m2, m3));
            mx = fmaxf(mx, __shfl_xor(mx, 16));
            mx = fmaxf(mx, __shfl_xor(mx, 32));
            const float m_new = fmaxf(m_run[qg], mx);
            const float alpha = __expf(m_run[qg] - m_new);
            m_run[qg] = m_new;

            float rs = 0.f;
#pragma unroll
            for (int nt = 0; nt < 4; nt++) {
#pragma unroll
                for (int i = 0; i < 2; i++) {
                    float p0 = __expf(s[qg][nt][2 * i]     - m_new);
                    float p1 = __expf(s[qg][nt][2 * i + 1] - m_new);
                    rs += p0 + p1;
                    Pw[(qg * 16 + l16) * PROW + nt * 8 + quad * 2 + i] = pack2(p0, p1);
                }
            }
            rs += __shfl_xor(rs, 16);
            rs += __shfl_xor(rs, 32);
            l_run[qg] = l_run[qg] * alpha + rs;

#pragma unroll
            for (int ht = 0; ht < 4; ht++)
#pragma unroll
                for (int r = 0; r < 4; r++) o[qg * 4 + ht][r] *= alpha;
        }

        // O^T += V^T * P^T (V frags shared across q-groups)
#pragma unroll
        for (int ks = 0; ks < 2; ks++) {
#pragma unroll
            for (int qg = 0; qg < 2; qg++) {
                bf16x8 pB = __builtin_bit_cast(bf16x8,
                    *(const u16x8*)(&Pw[(qg * 16 + l16) * PROW + ks * 16 + quad * 4]));
#pragma unroll
                for (int ht = 0; ht < 4; ht++)
                    o[qg * 4 + ht] = __builtin_amdgcn_mfma_f32_16x16x32_bf16(
                        vf[ht * 2 + ks], pB, o[qg * 4 + ht], 0, 0, 0);
            }
        }
    }

    // ---- 4-way LSE merge (O partials bf16) ----
#pragma unroll
    for (int qg = 0; qg < 2; qg++) {
#pragma unroll
        for (int ht = 0; ht < 4; ht++)
#pragma unroll
            for (int r = 0; r < 4; r++)
                Om_[(wave * 32 + qg * 16 + l16) * OMS2 + ht * 16 + quad * 4 + r] =
                    f2bf(o[qg * 4 + ht][r]);
        if (quad == 0) {
            mred_[wave][qg * 16 + l16] = m_run[qg];
            lred_[wave][qg * 16 + l16] = l_run[qg];
        }
    }
    __syncthreads();

    // finalize: thread -> (q, h); coalesced out write
    const int hcol = tid & 63;
    const int qr0  = tid >> 6;   // 0..3
#pragma unroll
    for (int qq = 0; qq < 8; qq++) {
        const int q = qr0 + qq * 4;
        float M = -1e30f;
#pragma unroll
        for (int w = 0; w < 4; w++) M = fmaxf(M, mred_[w][q]);
        float lt = 0.f, ov = 0.f;
#pragma unroll
        for (int w = 0; w < 4; w++) {
            float e = __expf(mred_[w][q] - M);
            lt += e * lred_[w][q];
            ov += e * bf2f(Om_[(w * 32 + q) * OMS2 + hcol]);
        }
        out[((size_t)b * T_ + q0 + q) * H_ + hcol] = ov / lt;
    }
}

// ---------------------------------------------------------------------------
extern "C" void kernel_launch(void* const* d_in, const int* in_sizes, int n_in,
                              void* d_out, int out_size, void* d_ws, size_t ws_size,
                              hipStream_t stream) {
    const float* x  = (const float*)d_in[0];
    const float* Wq = (const float*)d_in[1];
    const float* Wk = (const float*)d_in[2];
    const float* Wv = (const float*)d_in[3];
    float* out = (float*)d_out;

    unsigned short* Qf  = (unsigned short*)d_ws;
    unsigned short* Kf  = Qf + (size_t)B_ * T_ * H_;
    unsigned short* Vf  = Kf + (size_t)B_ * T_ * H_;
    unsigned short* Wtf = Vf + (size_t)B_ * T_ * H_;

    cast_weights<<<(192 * C_) / 256, 256, 0, stream>>>(Wq, Wk, Wv, Wtf);
    qkv_proj<<<B_ * T_ / 64, 512, 0, stream>>>(x, Wtf, Qf, Kf, Vf);
    attn<<<B_ * (T_ / 32), 256, 0, stream>>>(Qf, Kf, Vf, out);
}

// Round 10
// 138.038 us; speedup vs baseline: 1.1694x; 1.0225x over previous
//
#include <hip/hip_runtime.h>

// Problem constants (reference: B=8, T=2048, C=1024, H=64)
#define B_ 8
#define T_ 2048
#define C_ 1024
#define H_ 64

typedef __bf16 bf16x8 __attribute__((ext_vector_type(8)));
typedef float  f32x4  __attribute__((ext_vector_type(4)));
typedef unsigned short u16x8 __attribute__((ext_vector_type(8)));

// round-half-up f32 -> bf16 bits
__device__ __forceinline__ unsigned short f2bf(float f) {
    unsigned u = __builtin_bit_cast(unsigned, f);
    u += 0x8000u;
    return (unsigned short)(u >> 16);
}

__device__ __forceinline__ float bf2f(unsigned short v) {
    unsigned u = ((unsigned)v) << 16;
    return __builtin_bit_cast(float, u);
}

__device__ __forceinline__ unsigned pack2(float lo, float hi) {
    unsigned a = __builtin_bit_cast(unsigned, lo) + 0x8000u;
    unsigned b = __builtin_bit_cast(unsigned, hi) + 0x8000u;
    return (a >> 16) | (b & 0xffff0000u);
}

union U8 { unsigned u32[4]; u16x8 v; };

__device__ __forceinline__ u16x8 cvt8(float4 f0, float4 f1) {
    U8 r;
    r.u32[0] = pack2(f0.x, f0.y);
    r.u32[1] = pack2(f0.z, f0.w);
    r.u32[2] = pack2(f1.x, f1.y);
    r.u32[3] = pack2(f1.z, f1.w);
    return r.v;
}

__device__ __forceinline__ bf16x8 load8_bf(const unsigned short* p) {
    return __builtin_bit_cast(bf16x8, *(const u16x8*)p);
}

// Async global->LDS, 16B per lane, no destination VGPRs (vmcnt-counted).
// Dest = wave-uniform base + lane*16 (linear); source addr is per-lane.
__device__ __forceinline__ void gload_lds16(const float* g, float* l) {
    __builtin_amdgcn_global_load_lds(
        (const __attribute__((address_space(1))) unsigned int*)g,
        (__attribute__((address_space(3))) unsigned int*)l, 16, 0, 0);
}

// Fragment-major layouts (contiguous 1KB-per-wave loads):
//   Qf/Kf[b][t16][part][l16*32 + quad*8 + j]   (t16 = seq/16, part = h/32)
//   Vf[b][s32][ht][l16*32 + quad*8 + j]        (s32 = seq/32, ht = h/16)
//   Wtf[nt][kk][l16*32 + quad*8 + j]           (nt = ncol/16 of 192, kk = c/32)

// ---------------------------------------------------------------------------
// Kernel 0: pack Wq,Wk,Wv (fp32 [C][H]) straight into fragment-major Wtf.
// ---------------------------------------------------------------------------
__global__ void cast_weights(const float* __restrict__ Wq,
                             const float* __restrict__ Wk,
                             const float* __restrict__ Wv,
                             unsigned short* __restrict__ Wtf) {
    int idx = blockIdx.x * blockDim.x + threadIdx.x;   // 0 .. 192*1024-1
    int n   = idx % 192;        // global out col
    int c   = idx / 192;        // k index
    int w   = n >> 6;
    int h   = n & 63;
    const float* W = (w == 0) ? Wq : (w == 1) ? Wk : Wv;
    int nt = n >> 4, l16 = n & 15;
    int kk = c >> 5, quad = (c >> 3) & 3, j = c & 7;
    Wtf[(size_t)(nt * 32 + kk) * 512 + l16 * 32 + quad * 8 + j] =
        f2bf(W[(size_t)c * H_ + h]);
}

// ---------------------------------------------------------------------------
// Kernel 1: fused QKV projection, v16 (unchanged, best-known).
// Counted-vmcnt 4-buffer pipeline + A/B LDS involution swizzles.
// ---------------------------------------------------------------------------
#define NCH 16   // K chunks (1024 / 64)

__global__ __launch_bounds__(512, 2) void qkv_proj(
        const float* __restrict__ x,
        const unsigned short* __restrict__ Wtf,
        unsigned short* __restrict__ Qf,
        unsigned short* __restrict__ Kf,
        unsigned short* __restrict__ Vf) {
    __shared__ __attribute__((aligned(16))) char smem[163840];  // 160 KB
    // A buffers: 4 x 16 KB at [0, 64K); B buffers: 4 x 24 KB at [64K, 160K)
    unsigned short* E = (unsigned short*)smem;                  // 24 KB overlay

    const int tid   = threadIdx.x;
    const int w     = tid >> 6;        // wave 0..7
    const int strip = w & 3;           // m-strip (16 rows)
    const int nh    = w >> 2;          // n-half (6 n-tiles = 96 cols)
    const int lane  = tid & 63;
    const int l16   = lane & 15;
    const int quad  = lane >> 4;
    const size_t rblk = (size_t)blockIdx.x * 64;
    const int bb    = (int)(rblk >> 11);
    const int tloc0 = (int)(rblk & (T_ - 1));
    const int t16_0 = tloc0 >> 4;
    const int s32_0 = tloc0 >> 5;
    const int xsw   = l16 & 7;
    // B slot involution: lane's fragment granule s=l16*4+quad lives at p(s);
    // (s>>3) == l16>>1 for s = 4*l16+quad.
    const int bs8   = (((l16 * 4 + quad) ^ (l16 >> 1)) * 8);   // u16 offset

    // ---- stage chunk c into buffer c&3: 40 x 1KB issues, 5 per wave ----
    auto stage = [&](int c) {
        float* Ab          = (float*)(smem + (c & 3) * 16384);
        char*  Bb          = smem + 65536 + (c & 3) * 24576;
#pragma unroll
        for (int q = 0; q < 5; q++) {
            int j = w * 5 + q;                 // 0..39
            if (j < 16) {                      // A: 64x64 fp32, swz source
                int row  = j * 4 + (lane >> 4);    // 0..63 (block-local)
                int slot = lane & 15;              // 16B slot within row
                int g    = slot ^ (row & 7);       // global granule16
                gload_lds16(x + (rblk + row) * C_ + c * 64 + g * 4,
                            Ab + j * 256);
            } else {                           // B: 24 x 1KB frag blocks
                int jb = j - 16;               // 0..23
                int nt = jb >> 1, kkl = jb & 1;
                int sl = lane ^ (lane >> 3);   // source granule p(lane)
                gload_lds16(
                    (const float*)(Wtf + ((size_t)nt * 32 + c * 2 + kkl) * 512
                                   + (size_t)sl * 8),
                    (float*)(Bb + jb * 1024));
            }
        }
    };

    f32x4 acc[6];
#pragma unroll
    for (int i = 0; i < 6; i++) acc[i] = (f32x4){0.f, 0.f, 0.f, 0.f};

    stage(0); stage(1); stage(2);          // 15 issues/wave in flight

    for (int c = 0; c < NCH; c++) {
        // counted wait: chunk c retired; newer chunks stay in flight
        if (c < NCH - 2)       asm volatile("s_waitcnt vmcnt(10)" ::: "memory");
        else if (c == NCH - 2) asm volatile("s_waitcnt vmcnt(5)"  ::: "memory");
        else                   asm volatile("s_waitcnt vmcnt(0)"  ::: "memory");
        __builtin_amdgcn_s_barrier();
        __builtin_amdgcn_sched_barrier(0);

        if (c + 3 < NCH) stage(c + 3);     // writes buf (c-1)&3 (dead)

        const float* Ab = (const float*)(smem + (c & 3) * 16384)
                          + (strip * 16 + l16) * 64;
        const unsigned short* Bb =
            (const unsigned short*)(smem + 65536 + (c & 3) * 24576);
#pragma unroll
        for (int kk = 0; kk < 2; kk++) {
            int g0 = kk * 8 + quad * 2;        // granule16 of lane's A frag
            float4 f0 = *(const float4*)(Ab + ((g0    ) ^ xsw) * 4);
            float4 f1 = *(const float4*)(Ab + ((g0 + 1) ^ xsw) * 4);
            bf16x8 a0 = __builtin_bit_cast(bf16x8, cvt8(f0, f1));
#pragma unroll
            for (int i = 0; i < 6; i++) {
                bf16x8 b = load8_bf(Bb + ((nh * 6 + i) * 2 + kk) * 512 + bs8);
                acc[i] = __builtin_amdgcn_mfma_f32_16x16x32_bf16(a0, b, acc[i], 0, 0, 0);
            }
        }
    }

    // ---- epilogue: E overlays buf0 (dead; all DMA drained at c=15) ----
    {
        const int g   = strip >> 1;
        const int st2 = strip & 1;
        unsigned short* Eg = E + g * 6144;
#pragma unroll
        for (int i = 0; i < 6; i++) {
            int nt = nh * 6 + i;
#pragma unroll
            for (int r = 0; r < 4; r++) {
                unsigned short bv = f2bf(acc[i][r]);
                int off;
                if (nt < 4) {                // Q: chunk = st2*2 + part
                    off = (st2 * 2 + (nt >> 1)) * 512 +
                          (quad * 4 + r) * 32 + (nt & 1) * 16 + l16;
                } else if (nt < 8) {         // K
                    int nk = nt - 4;
                    off = 2048 + (st2 * 2 + (nk >> 1)) * 512 +
                          (quad * 4 + r) * 32 + (nk & 1) * 16 + l16;
                } else {                     // V (transposed): h-major, s minor
                    int ht = nt - 8;
                    off = 4096 + ht * 512 + l16 * 32 + st2 * 16 + quad * 4 + r;
                }
                Eg[off] = bv;
            }
        }
    }
    __syncthreads();

    // ---- copy-out: 2 groups x 12 chunks x 64 granules = 1536; 3/thread ----
#pragma unroll
    for (int c3 = 0; c3 < 3; c3++) {
        int gi  = c3 * 512 + tid;            // 0..1535
        int grp = (gi >= 768) ? 1 : 0;
        int wi  = gi - grp * 768;            // 0..767
        int ch  = wi >> 6;                   // 0..11
        int gg  = wi & 63;
        const unsigned short* src = E + grp * 6144 + ch * 512 + gg * 8;
        int t16g = t16_0 + grp * 2;
        int s32g = s32_0 + grp;
        unsigned short* dst;
        if (ch < 4) {
            dst = Qf + ((size_t)(bb * 128 + t16g + (ch >> 1)) * 2 + (ch & 1)) * 512;
        } else if (ch < 8) {
            int c2 = ch - 4;
            dst = Kf + ((size_t)(bb * 128 + t16g + (c2 >> 1)) * 2 + (c2 & 1)) * 512;
        } else {
            dst = Vf + ((size_t)(bb * 64 + s32g) * 4 + (ch - 8)) * 512;
        }
        *(u16x8*)(dst + gg * 8) = *(const u16x8*)src;
    }
}

// ---------------------------------------------------------------------------
// Kernel 2: flash attention, v9 — LOAD-BALANCED q-tile pairing.
// v8's grid (512 blocks, one qt32 each) had a 1:32 work spread (tdiag =
// qt32>>1 + 1 KV-iters) over exactly 2 blocks/CU with no re-balance pool:
// worst CU ~12 tile-iters/SIMD vs 8.25 mean -> wall stretched ~1.45x.
// v9: 256 blocks x 512 threads. Waves 0-3 process q-tile j, waves 4-7
// process q-tile 63-j (j = blk>>3): per-block total = (j>>1)+((63-j)>>1)+2
// ~ 33 tile-iters, CONSTANT over all blocks -> every SIMD hosts one light
// + one heavy wave, ~8.25 iters. Same 8 waves/CU residency; t-loop body
// byte-identical (no barriers inside, halves fully independent); LDS
// doubled (69.6 KB). XCD batch-affinity preserved (b = blk&7).
// ---------------------------------------------------------------------------
#define PROW 33   // u32 per P^T row
#define OMS2 66   // u16 per O-merge row

__global__ __launch_bounds__(512) void attn(
        const unsigned short* __restrict__ Qf,
        const unsigned short* __restrict__ Kf,
        const unsigned short* __restrict__ Vf,
        float* __restrict__ out) {
    __shared__ unsigned int ps_[8 * 32 * PROW];     // 33.8 KB
    __shared__ unsigned short Om_[8 * 32 * OMS2];   // 33.8 KB
    __shared__ float mred_[8][32];
    __shared__ float lred_[8][32];

    const int tid  = threadIdx.x;
    const int wave = tid >> 6;            // 0..7
    const int half = wave >> 2;           // 0 = light tile j, 1 = heavy 63-j
    const int wv4  = wave & 3;            // KV-split index 0..3 within half
    const int lane = tid & 63;
    const int l16  = lane & 15;
    const int quad = lane >> 4;
    const int b    = blockIdx.x & 7;      // XCD-affinity: batch = XCD
    const int jp   = blockIdx.x >> 3;     // pair index 0..31
    const int qt32 = half ? (63 - jp) : jp;
    const int q0   = qt32 * 32;
    const int tdiag = qt32 >> 1;          // diagonal 64-key tile index

    const int loff = l16 * 32 + quad * 8;

    // Q as B-operand, two q-groups
    bf16x8 qf[2][2];
#pragma unroll
    for (int qg = 0; qg < 2; qg++) {
        const unsigned short* Qfb = Qf + (size_t)((b * 128 + qt32 * 2 + qg) * 2) * 512;
        qf[qg][0] = load8_bf(Qfb + loff);
        qf[qg][1] = load8_bf(Qfb + 512 + loff);
    }

    f32x4 o[8];   // [qg*4 + ht]
#pragma unroll
    for (int i = 0; i < 8; i++) o[i] = (f32x4){0.f, 0.f, 0.f, 0.f};
    float m_run[2] = {-1e30f, -1e30f}, l_run[2] = {0.f, 0.f};

    const float scale = 0.125f;  // 1/sqrt(H)
    const unsigned short* Kfb = Kf + (size_t)b * 128 * 1024;
    const unsigned short* Vfb = Vf + (size_t)b * 64 * 2048;
    unsigned int* Pw = &ps_[wave * 32 * PROW];

    for (int t = wv4; t <= tdiag; t += 4) {
        // V^T A-frags: contiguous 1KB loads, issued EARLY (softmax-independent)
        bf16x8 vf[8];
#pragma unroll
        for (int ks = 0; ks < 2; ks++)
#pragma unroll
            for (int ht = 0; ht < 4; ht++)
                vf[ht * 2 + ks] = load8_bf(
                    Vfb + ((size_t)(t * 2 + ks) * 4 + ht) * 512 + loff);

        // S^T = K * Q^T for both q-groups (K frags shared)
        f32x4 s[2][4];
#pragma unroll
        for (int nt = 0; nt < 4; nt++) {
            const unsigned short* kp = Kfb + (size_t)(t * 4 + nt) * 1024;
            bf16x8 kf0 = load8_bf(kp + loff);
            bf16x8 kf1 = load8_bf(kp + 512 + loff);
#pragma unroll
            for (int qg = 0; qg < 2; qg++) {
                f32x4 z = (f32x4){0.f, 0.f, 0.f, 0.f};
                z = __builtin_amdgcn_mfma_f32_16x16x32_bf16(kf0, qf[qg][0], z, 0, 0, 0);
                z = __builtin_amdgcn_mfma_f32_16x16x32_bf16(kf1, qf[qg][1], z, 0, 0, 0);
                s[qg][nt] = z;   // S^T[s = t*64+nt*16+quad*4+r][q = q0+qg*16+l16]
            }
        }

#pragma unroll
        for (int qg = 0; qg < 2; qg++)
#pragma unroll
            for (int nt = 0; nt < 4; nt++)
#pragma unroll
                for (int r = 0; r < 4; r++) s[qg][nt][r] *= scale;

        if (t == tdiag) {   // causal: mask s > q
#pragma unroll
            for (int qg = 0; qg < 2; qg++) {
                int q = q0 + qg * 16 + l16;
#pragma unroll
                for (int nt = 0; nt < 4; nt++)
#pragma unroll
                    for (int r = 0; r < 4; r++) {
                        int key = t * 64 + nt * 16 + quad * 4 + r;
                        if (key > q) s[qg][nt][r] = -1e30f;
                    }
            }
        }

        // per-lane softmax per q-group: in-lane tree + 2 cross-quad shuffles
#pragma unroll
        for (int qg = 0; qg < 2; qg++) {
            float m0 = fmaxf(fmaxf(s[qg][0][0], s[qg][0][1]), fmaxf(s[qg][0][2], s[qg][0][3]));
            float m1 = fmaxf(fmaxf(s[qg][1][0], s[qg][1][1]), fmaxf(s[qg][1][2], s[qg][1][3]));
            float m2 = fmaxf(fmaxf(s[qg][2][0], s[qg][2][1]), fmaxf(s[qg][2][2], s[qg][2][3]));
            float m3 = fmaxf(fmaxf(s[qg][3][0], s[qg][3][1]), fmaxf(s[qg][3][2], s[qg][3][3]));
            float mx = fmaxf(fmaxf(m0, m1), fmaxf(m2, m3));
            mx = fmaxf(mx, __shfl_xor(mx, 16));
            mx = fmaxf(mx, __shfl_xor(mx, 32));
            const float m_new = fmaxf(m_run[qg], mx);
            const float alpha = __expf(m_run[qg] - m_new);
            m_run[qg] = m_new;

            float rs = 0.f;
#pragma unroll
            for (int nt = 0; nt < 4; nt++) {
#pragma unroll
                for (int i = 0; i < 2; i++) {
                    float p0 = __expf(s[qg][nt][2 * i]     - m_new);
                    float p1 = __expf(s[qg][nt][2 * i + 1] - m_new);
                    rs += p0 + p1;
                    Pw[(qg * 16 + l16) * PROW + nt * 8 + quad * 2 + i] = pack2(p0, p1);
                }
            }
            rs += __shfl_xor(rs, 16);
            rs += __shfl_xor(rs, 32);
            l_run[qg] = l_run[qg] * alpha + rs;

#pragma unroll
            for (int ht = 0; ht < 4; ht++)
#pragma unroll
                for (int r = 0; r < 4; r++) o[qg * 4 + ht][r] *= alpha;
        }

        // O^T += V^T * P^T (V frags shared across q-groups)
#pragma unroll
        for (int ks = 0; ks < 2; ks++) {
#pragma unroll
            for (int qg = 0; qg < 2; qg++) {
                bf16x8 pB = __builtin_bit_cast(bf16x8,
                    *(const u16x8*)(&Pw[(qg * 16 + l16) * PROW + ks * 16 + quad * 4]));
#pragma unroll
                for (int ht = 0; ht < 4; ht++)
                    o[qg * 4 + ht] = __builtin_amdgcn_mfma_f32_16x16x32_bf16(
                        vf[ht * 2 + ks], pB, o[qg * 4 + ht], 0, 0, 0);
            }
        }
    }

    // ---- 4-way LSE merge per half (O partials bf16) ----
#pragma unroll
    for (int qg = 0; qg < 2; qg++) {
#pragma unroll
        for (int ht = 0; ht < 4; ht++)
#pragma unroll
            for (int r = 0; r < 4; r++)
                Om_[(wave * 32 + qg * 16 + l16) * OMS2 + ht * 16 + quad * 4 + r] =
                    f2bf(o[qg * 4 + ht][r]);
        if (quad == 0) {
            mred_[wave][qg * 16 + l16] = m_run[qg];
            lred_[wave][qg * 16 + l16] = l_run[qg];
        }
    }
    __syncthreads();

    // finalize: threads 0-255 -> half 0's tile, 256-511 -> half 1's tile
    const int half2 = tid >> 8;
    const int t2    = tid & 255;
    const int hcol  = t2 & 63;
    const int qr0   = t2 >> 6;   // 0..3
    const int qt32f = half2 ? (63 - jp) : jp;
    const int q0f   = qt32f * 32;
#pragma unroll
    for (int qq = 0; qq < 8; qq++) {
        const int q = qr0 + qq * 4;
        float M = -1e30f;
#pragma unroll
        for (int w = 0; w < 4; w++) M = fmaxf(M, mred_[half2 * 4 + w][q]);
        float lt = 0.f, ov = 0.f;
#pragma unroll
        for (int w = 0; w < 4; w++) {
            float e = __expf(mred_[half2 * 4 + w][q] - M);
            lt += e * lred_[half2 * 4 + w][q];
            ov += e * bf2f(Om_[((half2 * 4 + w) * 32 + q) * OMS2 + hcol]);
        }
        out[((size_t)b * T_ + q0f + q) * H_ + hcol] = ov / lt;
    }
}

// ---------------------------------------------------------------------------
extern "C" void kernel_launch(void* const* d_in, const int* in_sizes, int n_in,
                              void* d_out, int out_size, void* d_ws, size_t ws_size,
                              hipStream_t stream) {
    const float* x  = (const float*)d_in[0];
    const float* Wq = (const float*)d_in[1];
    const float* Wk = (const float*)d_in[2];
    const float* Wv = (const float*)d_in[3];
    float* out = (float*)d_out;

    unsigned short* Qf  = (unsigned short*)d_ws;
    unsigned short* Kf  = Qf + (size_t)B_ * T_ * H_;
    unsigned short* Vf  = Kf + (size_t)B_ * T_ * H_;
    unsigned short* Wtf = Vf + (size_t)B_ * T_ * H_;

    cast_weights<<<(192 * C_) / 256, 256, 0, stream>>>(Wq, Wk, Wv, Wtf);
    qkv_proj<<<B_ * T_ / 64, 512, 0, stream>>>(x, Wtf, Qf, Kf, Vf);
    attn<<<B_ * (T_ / 64), 512, 0, stream>>>(Qf, Kf, Vf, out);
}

// Round 11
// 136.790 us; speedup vs baseline: 1.1801x; 1.0091x over previous
//
#include <hip/hip_runtime.h>

// Problem constants (reference: B=8, T=2048, C=1024, H=64)
#define B_ 8
#define T_ 2048
#define C_ 1024
#define H_ 64

typedef __bf16 bf16x8 __attribute__((ext_vector_type(8)));
typedef float  f32x4  __attribute__((ext_vector_type(4)));
typedef unsigned short u16x8 __attribute__((ext_vector_type(8)));

// round-half-up f32 -> bf16 bits
__device__ __forceinline__ unsigned short f2bf(float f) {
    unsigned u = __builtin_bit_cast(unsigned, f);
    u += 0x8000u;
    return (unsigned short)(u >> 16);
}

__device__ __forceinline__ float bf2f(unsigned short v) {
    unsigned u = ((unsigned)v) << 16;
    return __builtin_bit_cast(float, u);
}

__device__ __forceinline__ unsigned pack2(float lo, float hi) {
    unsigned a = __builtin_bit_cast(unsigned, lo) + 0x8000u;
    unsigned b = __builtin_bit_cast(unsigned, hi) + 0x8000u;
    return (a >> 16) | (b & 0xffff0000u);
}

union U8 { unsigned u32[4]; u16x8 v; };

__device__ __forceinline__ u16x8 cvt8(float4 f0, float4 f1) {
    U8 r;
    r.u32[0] = pack2(f0.x, f0.y);
    r.u32[1] = pack2(f0.z, f0.w);
    r.u32[2] = pack2(f1.x, f1.y);
    r.u32[3] = pack2(f1.z, f1.w);
    return r.v;
}

__device__ __forceinline__ bf16x8 load8_bf(const unsigned short* p) {
    return __builtin_bit_cast(bf16x8, *(const u16x8*)p);
}

// Async global->LDS, 16B per lane, no destination VGPRs (vmcnt-counted).
// Dest = wave-uniform base + lane*16 (linear); source addr is per-lane.
__device__ __forceinline__ void gload_lds16(const float* g, float* l) {
    __builtin_amdgcn_global_load_lds(
        (const __attribute__((address_space(1))) unsigned int*)g,
        (__attribute__((address_space(3))) unsigned int*)l, 16, 0, 0);
}

// Fragment-major layouts (contiguous 1KB-per-wave loads):
//   Qf/Kf[b][t16][part][l16*32 + quad*8 + j]   (t16 = seq/16, part = h/32)
//   Vf[b][s32][ht][l16*32 + quad*8 + j]        (s32 = seq/32, ht = h/16)
//   Wtf[nt][kk][l16*32 + quad*8 + j]           (nt = ncol/16 of 192, kk = c/32)

// ---------------------------------------------------------------------------
// Kernel 0: pack Wq,Wk,Wv (fp32 [C][H]) straight into fragment-major Wtf.
// ---------------------------------------------------------------------------
__global__ void cast_weights(const float* __restrict__ Wq,
                             const float* __restrict__ Wk,
                             const float* __restrict__ Wv,
                             unsigned short* __restrict__ Wtf) {
    int idx = blockIdx.x * blockDim.x + threadIdx.x;   // 0 .. 192*1024-1
    int n   = idx % 192;        // global out col
    int c   = idx / 192;        // k index
    int w   = n >> 6;
    int h   = n & 63;
    const float* W = (w == 0) ? Wq : (w == 1) ? Wk : Wv;
    int nt = n >> 4, l16 = n & 15;
    int kk = c >> 5, quad = (c >> 3) & 3, j = c & 7;
    Wtf[(size_t)(nt * 32 + kk) * 512 + l16 * 32 + quad * 8 + j] =
        f2bf(W[(size_t)c * H_ + h]);
}

// ---------------------------------------------------------------------------
// Kernel 1: fused QKV projection, v18 — v14 bodies at 2 BLOCKS/CU.
// Post-mortem chain: v14/v15/v16 all ~40us at 1 block/CU with ~6300cy/chunk
// wall vs ~1200cy compute+transfer. m97 runs the SAME drain-per-step
// structure at 874 TF because ~3 blocks/CU let the CU swap to another block
// during the barrier drain (m114 implicit overlap). Source-level pipelining
// (v15 counted vmcnt) gained ~2us only — the compiler orders ds_reads after
// outstanding LDS-writing DMAs anyway. The fix is TLP, not ILP:
//   block = 32 rows x 192 cols, 256 thr (4 waves = 2 m-strips x 2 n-halves)
//   LDS 64 KB (A 2x8K dbuf + B 2x24K dbuf; E 12K overlay) -> 2 blocks/CU
//   grid = B*T/32 = 512 = 2 blocks/CU; plain __syncthreads per chunk —
//   the co-resident block hides the drain.
// Stage/compute bodies verbatim from v14/v16 (A xsw swizzle, B involution);
// epilogue/copy-out verbatim from v10 (32-row, harness-verified).
// ---------------------------------------------------------------------------
#define NCH 16   // K chunks (1024 / 64)

__global__ __launch_bounds__(256, 2) void qkv_proj(
        const float* __restrict__ x,
        const unsigned short* __restrict__ Wtf,
        unsigned short* __restrict__ Qf,
        unsigned short* __restrict__ Kf,
        unsigned short* __restrict__ Vf) {
    __shared__ __attribute__((aligned(16))) char smem[65536];   // 64 KB
    // A buffers: 2 x 8 KB at [0, 16K); B buffers: 2 x 24 KB at [16K, 64K)
    unsigned short* E = (unsigned short*)smem;                  // 12 KB overlay

    const int tid   = threadIdx.x;
    const int w     = tid >> 6;        // wave 0..3
    const int strip = w & 1;           // m-strip (16 rows)
    const int nh    = w >> 1;          // n-half (6 n-tiles = 96 cols)
    const int lane  = tid & 63;
    const int l16   = lane & 15;
    const int quad  = lane >> 4;
    const size_t rblk = (size_t)blockIdx.x * 32;
    const int bb    = (int)(rblk >> 11);
    const int tloc0 = (int)(rblk & (T_ - 1));
    const int t16_0 = tloc0 >> 4;
    const int s32_0 = tloc0 >> 5;
    const int xsw   = l16 & 7;
    // B slot involution p(s) = s ^ (s>>3); for s = 4*l16+quad, s>>3 = l16>>1.
    const int bs8   = (((l16 * 4 + quad) ^ (l16 >> 1)) * 8);   // u16 offset

    // ---- stage chunk c into buffer c&1: 32 x 1KB issues, 8 per wave ----
    auto stage = [&](int c) {
        float* Ab = (float*)(smem + (c & 1) * 8192);
        char*  Bb = smem + 16384 + (c & 1) * 24576;
#pragma unroll
        for (int q = 0; q < 8; q++) {
            int j = w * 8 + q;                 // 0..31
            if (j < 8) {                       // A: 32x64 fp32, swz source
                int row  = j * 4 + (lane >> 4);    // 0..31 (block-local)
                int slot = lane & 15;              // 16B slot within row
                int g    = slot ^ (row & 7);       // global granule16
                gload_lds16(x + (rblk + row) * C_ + c * 64 + g * 4,
                            Ab + j * 256);
            } else {                           // B: 24 x 1KB frag blocks
                int jb = j - 8;                // 0..23
                int nt = jb >> 1, kkl = jb & 1;
                int sl = lane ^ (lane >> 3);   // source granule p(lane)
                gload_lds16(
                    (const float*)(Wtf + ((size_t)nt * 32 + c * 2 + kkl) * 512
                                   + (size_t)sl * 8),
                    (float*)(Bb + jb * 1024));
            }
        }
    };

    f32x4 acc[6];
#pragma unroll
    for (int i = 0; i < 6; i++) acc[i] = (f32x4){0.f, 0.f, 0.f, 0.f};

    stage(0);
    __syncthreads();                   // chunk 0 landed

    for (int c = 0; c < NCH; c++) {
        if (c < NCH - 1) stage(c + 1);     // flies under compute + drain

        const float* Ab = (const float*)(smem + (c & 1) * 8192)
                          + (strip * 16 + l16) * 64;
        const unsigned short* Bb =
            (const unsigned short*)(smem + 16384 + (c & 1) * 24576);
#pragma unroll
        for (int kk = 0; kk < 2; kk++) {
            int g0 = kk * 8 + quad * 2;        // granule16 of lane's A frag
            float4 f0 = *(const float4*)(Ab + ((g0    ) ^ xsw) * 4);
            float4 f1 = *(const float4*)(Ab + ((g0 + 1) ^ xsw) * 4);
            bf16x8 a0 = __builtin_bit_cast(bf16x8, cvt8(f0, f1));
#pragma unroll
            for (int i = 0; i < 6; i++) {
                bf16x8 b = load8_bf(Bb + ((nh * 6 + i) * 2 + kk) * 512 + bs8);
                acc[i] = __builtin_amdgcn_mfma_f32_16x16x32_bf16(a0, b, acc[i], 0, 0, 0);
            }
        }
        __syncthreads();   // drain; co-resident block computes meanwhile
    }

    // ---- epilogue (v10-verified): E = Q 4x512 | K 4x512 | V 4x512 ----
    // acc[i] elem (l16,quad,r) = out[rblk + strip*16 + quad*4 + r][nt*16+l16],
    // nt = nh*6 + i.
#pragma unroll
    for (int i = 0; i < 6; i++) {
        int nt = nh * 6 + i;
#pragma unroll
        for (int r = 0; r < 4; r++) {
            unsigned short bv = f2bf(acc[i][r]);
            int off;
            if (nt < 4) {                // Q: chunk = strip*2 + part
                off = (strip * 2 + (nt >> 1)) * 512 +
                      (quad * 4 + r) * 32 + (nt & 1) * 16 + l16;
            } else if (nt < 8) {         // K
                int nk = nt - 4;
                off = 2048 + (strip * 2 + (nk >> 1)) * 512 +
                      (quad * 4 + r) * 32 + (nk & 1) * 16 + l16;
            } else {                     // V (transposed): h-major, s minor
                int ht = nt - 8;
                off = 4096 + ht * 512 + l16 * 32 + strip * 16 + quad * 4 + r;
            }
            E[off] = bv;
        }
    }
    __syncthreads();

    // ---- copy-out (v10-verified): 12 chunks x 64 granules; 3/thread ----
#pragma unroll
    for (int c3 = 0; c3 < 3; c3++) {
        int gi = c3 * 256 + tid;         // 0..767
        int ch = gi >> 6;
        int g  = gi & 63;
        unsigned short* dst;
        if (ch < 4) {
            dst = Qf + ((size_t)(bb * 128 + t16_0 + (ch >> 1)) * 2 + (ch & 1)) * 512;
        } else if (ch < 8) {
            int c2 = ch - 4;
            dst = Kf + ((size_t)(bb * 128 + t16_0 + (c2 >> 1)) * 2 + (c2 & 1)) * 512;
        } else {
            dst = Vf + ((size_t)(bb * 64 + s32_0) * 4 + (ch - 8)) * 512;
        }
        *(u16x8*)(dst + g * 8) = *(const u16x8*)(&E[ch * 512 + g * 8]);
    }
}

// ---------------------------------------------------------------------------
// Kernel 2: flash attention, v9 — LOAD-BALANCED q-tile pairing (unchanged).
// 256 blocks x 512 threads; waves 0-3 do q-tile j, waves 4-7 do 63-j:
// constant ~33 tile-iters per block. XCD batch-affinity (b = blk&7).
// ---------------------------------------------------------------------------
#define PROW 33   // u32 per P^T row
#define OMS2 66   // u16 per O-merge row

__global__ __launch_bounds__(512) void attn(
        const unsigned short* __restrict__ Qf,
        const unsigned short* __restrict__ Kf,
        const unsigned short* __restrict__ Vf,
        float* __restrict__ out) {
    __shared__ unsigned int ps_[8 * 32 * PROW];     // 33.8 KB
    __shared__ unsigned short Om_[8 * 32 * OMS2];   // 33.8 KB
    __shared__ float mred_[8][32];
    __shared__ float lred_[8][32];

    const int tid  = threadIdx.x;
    const int wave = tid >> 6;            // 0..7
    const int half = wave >> 2;           // 0 = light tile j, 1 = heavy 63-j
    const int wv4  = wave & 3;            // KV-split index 0..3 within half
    const int lane = tid & 63;
    const int l16  = lane & 15;
    const int quad = lane >> 4;
    const int b    = blockIdx.x & 7;      // XCD-affinity: batch = XCD
    const int jp   = blockIdx.x >> 3;     // pair index 0..31
    const int qt32 = half ? (63 - jp) : jp;
    const int q0   = qt32 * 32;
    const int tdiag = qt32 >> 1;          // diagonal 64-key tile index

    const int loff = l16 * 32 + quad * 8;

    // Q as B-operand, two q-groups
    bf16x8 qf[2][2];
#pragma unroll
    for (int qg = 0; qg < 2; qg++) {
        const unsigned short* Qfb = Qf + (size_t)((b * 128 + qt32 * 2 + qg) * 2) * 512;
        qf[qg][0] = load8_bf(Qfb + loff);
        qf[qg][1] = load8_bf(Qfb + 512 + loff);
    }

    f32x4 o[8];   // [qg*4 + ht]
#pragma unroll
    for (int i = 0; i < 8; i++) o[i] = (f32x4){0.f, 0.f, 0.f, 0.f};
    float m_run[2] = {-1e30f, -1e30f}, l_run[2] = {0.f, 0.f};

    const float scale = 0.125f;  // 1/sqrt(H)
    const unsigned short* Kfb = Kf + (size_t)b * 128 * 1024;
    const unsigned short* Vfb = Vf + (size_t)b * 64 * 2048;
    unsigned int* Pw = &ps_[wave * 32 * PROW];

    for (int t = wv4; t <= tdiag; t += 4) {
        // V^T A-frags: contiguous 1KB loads, issued EARLY (softmax-independent)
        bf16x8 vf[8];
#pragma unroll
        for (int ks = 0; ks < 2; ks++)
#pragma unroll
            for (int ht = 0; ht < 4; ht++)
                vf[ht * 2 + ks] = load8_bf(
                    Vfb + ((size_t)(t * 2 + ks) * 4 + ht) * 512 + loff);

        // S^T = K * Q^T for both q-groups (K frags shared)
        f32x4 s[2][4];
#pragma unroll
        for (int nt = 0; nt < 4; nt++) {
            const unsigned short* kp = Kfb + (size_t)(t * 4 + nt) * 1024;
            bf16x8 kf0 = load8_bf(kp + loff);
            bf16x8 kf1 = load8_bf(kp + 512 + loff);
#pragma unroll
            for (int qg = 0; qg < 2; qg++) {
                f32x4 z = (f32x4){0.f, 0.f, 0.f, 0.f};
                z = __builtin_amdgcn_mfma_f32_16x16x32_bf16(kf0, qf[qg][0], z, 0, 0, 0);
                z = __builtin_amdgcn_mfma_f32_16x16x32_bf16(kf1, qf[qg][1], z, 0, 0, 0);
                s[qg][nt] = z;   // S^T[s = t*64+nt*16+quad*4+r][q = q0+qg*16+l16]
            }
        }

#pragma unroll
        for (int qg = 0; qg < 2; qg++)
#pragma unroll
            for (int nt = 0; nt < 4; nt++)
#pragma unroll
                for (int r = 0; r < 4; r++) s[qg][nt][r] *= scale;

        if (t == tdiag) {   // causal: mask s > q
#pragma unroll
            for (int qg = 0; qg < 2; qg++) {
                int q = q0 + qg * 16 + l16;
#pragma unroll
                for (int nt = 0; nt < 4; nt++)
#pragma unroll
                    for (int r = 0; r < 4; r++) {
                        int key = t * 64 + nt * 16 + quad * 4 + r;
                        if (key > q) s[qg][nt][r] = -1e30f;
                    }
            }
        }

        // per-lane softmax per q-group: in-lane tree + 2 cross-quad shuffles
#pragma unroll
        for (int qg = 0; qg < 2; qg++) {
            float m0 = fmaxf(fmaxf(s[qg][0][0], s[qg][0][1]), fmaxf(s[qg][0][2], s[qg][0][3]));
            float m1 = fmaxf(fmaxf(s[qg][1][0], s[qg][1][1]), fmaxf(s[qg][1][2], s[qg][1][3]));
            float m2 = fmaxf(fmaxf(s[qg][2][0], s[qg][2][1]), fmaxf(s[qg][2][2], s[qg][2][3]));
            float m3 = fmaxf(fmaxf(s[qg][3][0], s[qg][3][1]), fmaxf(s[qg][3][2], s[qg][3][3]));
            float mx = fmaxf(fmaxf(m0, m1), fmaxf(m2, m3));
            mx = fmaxf(mx, __shfl_xor(mx, 16));
            mx = fmaxf(mx, __shfl_xor(mx, 32));
            const float m_new = fmaxf(m_run[qg], mx);
            const float alpha = __expf(m_run[qg] - m_new);
            m_run[qg] = m_new;

            float rs = 0.f;
#pragma unroll
            for (int nt = 0; nt < 4; nt++) {
#pragma unroll
                for (int i = 0; i < 2; i++) {
                    float p0 = __expf(s[qg][nt][2 * i]     - m_new);
                    float p1 = __expf(s[qg][nt][2 * i + 1] - m_new);
                    rs += p0 + p1;
                    Pw[(qg * 16 + l16) * PROW + nt * 8 + quad * 2 + i] = pack2(p0, p1);
                }
            }
            rs += __shfl_xor(rs, 16);
            rs += __shfl_xor(rs, 32);
            l_run[qg] = l_run[qg] * alpha + rs;

#pragma unroll
            for (int ht = 0; ht < 4; ht++)
#pragma unroll
                for (int r = 0; r < 4; r++) o[qg * 4 + ht][r] *= alpha;
        }

        // O^T += V^T * P^T (V frags shared across q-groups)
#pragma unroll
        for (int ks = 0; ks < 2; ks++) {
#pragma unroll
            for (int qg = 0; qg < 2; qg++) {
                bf16x8 pB = __builtin_bit_cast(bf16x8,
                    *(const u16x8*)(&Pw[(qg * 16 + l16) * PROW + ks * 16 + quad * 4]));
#pragma unroll
                for (int ht = 0; ht < 4; ht++)
                    o[qg * 4 + ht] = __builtin_amdgcn_mfma_f32_16x16x32_bf16(
                        vf[ht * 2 + ks], pB, o[qg * 4 + ht], 0, 0, 0);
            }
        }
    }

    // ---- 4-way LSE merge per half (O partials bf16) ----
#pragma unroll
    for (int qg = 0; qg < 2; qg++) {
#pragma unroll
        for (int ht = 0; ht < 4; ht++)
#pragma unroll
            for (int r = 0; r < 4; r++)
                Om_[(wave * 32 + qg * 16 + l16) * OMS2 + ht * 16 + quad * 4 + r] =
                    f2bf(o[qg * 4 + ht][r]);
        if (quad == 0) {
            mred_[wave][qg * 16 + l16] = m_run[qg];
            lred_[wave][qg * 16 + l16] = l_run[qg];
        }
    }
    __syncthreads();

    // finalize: threads 0-255 -> half 0's tile, 256-511 -> half 1's tile
    const int half2 = tid >> 8;
    const int t2    = tid & 255;
    const int hcol  = t2 & 63;
    const int qr0   = t2 >> 6;   // 0..3
    const int qt32f = half2 ? (63 - jp) : jp;
    const int q0f   = qt32f * 32;
#pragma unroll
    for (int qq = 0; qq < 8; qq++) {
        const int q = qr0 + qq * 4;
        float M = -1e30f;
#pragma unroll
        for (int w = 0; w < 4; w++) M = fmaxf(M, mred_[half2 * 4 + w][q]);
        float lt = 0.f, ov = 0.f;
#pragma unroll
        for (int w = 0; w < 4; w++) {
            float e = __expf(mred_[half2 * 4 + w][q] - M);
            lt += e * lred_[half2 * 4 + w][q];
            ov += e * bf2f(Om_[((half2 * 4 + w) * 32 + q) * OMS2 + hcol]);
        }
        out[((size_t)b * T_ + q0f + q) * H_ + hcol] = ov / lt;
    }
}

// ---------------------------------------------------------------------------
extern "C" void kernel_launch(void* const* d_in, const int* in_sizes, int n_in,
                              void* d_out, int out_size, void* d_ws, size_t ws_size,
                              hipStream_t stream) {
    const float* x  = (const float*)d_in[0];
    const float* Wq = (const float*)d_in[1];
    const float* Wk = (const float*)d_in[2];
    const float* Wv = (const float*)d_in[3];
    float* out = (float*)d_out;

    unsigned short* Qf  = (unsigned short*)d_ws;
    unsigned short* Kf  = Qf + (size_t)B_ * T_ * H_;
    unsigned short* Vf  = Kf + (size_t)B_ * T_ * H_;
    unsigned short* Wtf = Vf + (size_t)B_ * T_ * H_;

    cast_weights<<<(192 * C_) / 256, 256, 0, stream>>>(Wq, Wk, Wv, Wtf);
    qkv_proj<<<B_ * T_ / 32, 256, 0, stream>>>(x, Wtf, Qf, Kf, Vf);
    attn<<<B_ * (T_ / 64), 512, 0, stream>>>(Qf, Kf, Vf, out);
}

// Round 12
// 131.925 us; speedup vs baseline: 1.2236x; 1.0369x over previous
//
#include <hip/hip_runtime.h>

// Problem constants (reference: B=8, T=2048, C=1024, H=64)
#define B_ 8
#define T_ 2048
#define C_ 1024
#define H_ 64

typedef __bf16 bf16x8 __attribute__((ext_vector_type(8)));
typedef float  f32x4  __attribute__((ext_vector_type(4)));
typedef unsigned short u16x8 __attribute__((ext_vector_type(8)));

// round-half-up f32 -> bf16 bits
__device__ __forceinline__ unsigned short f2bf(float f) {
    unsigned u = __builtin_bit_cast(unsigned, f);
    u += 0x8000u;
    return (unsigned short)(u >> 16);
}

__device__ __forceinline__ float bf2f(unsigned short v) {
    unsigned u = ((unsigned)v) << 16;
    return __builtin_bit_cast(float, u);
}

__device__ __forceinline__ unsigned pack2(float lo, float hi) {
    unsigned a = __builtin_bit_cast(unsigned, lo) + 0x8000u;
    unsigned b = __builtin_bit_cast(unsigned, hi) + 0x8000u;
    return (a >> 16) | (b & 0xffff0000u);
}

union U8 { unsigned u32[4]; u16x8 v; };

__device__ __forceinline__ u16x8 cvt8(float4 f0, float4 f1) {
    U8 r;
    r.u32[0] = pack2(f0.x, f0.y);
    r.u32[1] = pack2(f0.z, f0.w);
    r.u32[2] = pack2(f1.x, f1.y);
    r.u32[3] = pack2(f1.z, f1.w);
    return r.v;
}

__device__ __forceinline__ bf16x8 load8_bf(const unsigned short* p) {
    return __builtin_bit_cast(bf16x8, *(const u16x8*)p);
}

// Async global->LDS, 16B per lane, no destination VGPRs (vmcnt-counted).
// Dest = wave-uniform base + lane*16 (linear); source addr is per-lane.
__device__ __forceinline__ void gload_lds16(const float* g, float* l) {
    __builtin_amdgcn_global_load_lds(
        (const __attribute__((address_space(1))) unsigned int*)g,
        (__attribute__((address_space(3))) unsigned int*)l, 16, 0, 0);
}

// Fragment-major layouts (contiguous 1KB-per-wave loads):
//   Qf/Kf[b][t16][part][l16*32 + quad*8 + j]   (t16 = seq/16, part = h/32)
//   Vf[b][s32][ht][l16*32 + quad*8 + j]        (s32 = seq/32, ht = h/16)
//   Wtf[nt][kk][l16*32 + quad*8 + j]           (nt = ncol/16 of 192, kk = c/32)

// ---------------------------------------------------------------------------
// Kernel 0: pack Wq,Wk,Wv into fragment-major Wtf  +  WARM x INTO L3.
// The harness re-poisons a 268 MB workspace every iteration at ~80% HBM
// peak — that evicts x (64 MB) from every L2 AND the 256 MB L3. qkv's
// per-chunk DMA chains then expose ~900cy COLD-miss latency per step,
// which is why ten structural qkv variants all measured ~40us at a fixed
// ~1 TB/s: the wall is the cold fetch, not the loop structure.
// Fix: grid-stride-read all of x here (2048 blocks -> thousands of waves,
// latency fully hidden, ~10us at streaming BW) and sink it via asm (rule
// #17, no DCE). x then sits in L3 and qkv's DMAs see L3-hit latency.
// ---------------------------------------------------------------------------
__global__ void cast_weights(const float* __restrict__ Wq,
                             const float* __restrict__ Wk,
                             const float* __restrict__ Wv,
                             unsigned short* __restrict__ Wtf,
                             const float* __restrict__ x) {
    int idx = blockIdx.x * blockDim.x + threadIdx.x;
    if (idx < 192 * 1024) {
        int n   = idx % 192;        // global out col
        int c   = idx / 192;        // k index
        int w   = n >> 6;
        int h   = n & 63;
        const float* W = (w == 0) ? Wq : (w == 1) ? Wk : Wv;
        int nt = n >> 4, l16 = n & 15;
        int kk = c >> 5, quad = (c >> 3) & 3, j = c & 7;
        Wtf[(size_t)(nt * 32 + kk) * 512 + l16 * 32 + quad * 8 + j] =
            f2bf(W[(size_t)c * H_ + h]);
    }
    // ---- x warm: grid-stride float4 read of all 64 MB, sunk, no stores ----
    const float4* x4 = (const float4*)x;
    const int n4     = B_ * T_ * C_ / 4;          // 4,194,304 float4
    const int stride = gridDim.x * blockDim.x;    // 524,288
    float s = 0.f;
    for (int i = idx; i < n4; i += stride) {      // 8 iters/thread
        float4 v = x4[i];
        s += v.x + v.y + v.z + v.w;
    }
    asm volatile("" :: "v"(s));                   // keep the reads live
}

// ---------------------------------------------------------------------------
// Kernel 1: fused QKV projection, v18 (unchanged, best-known).
// 32 rows x 192 cols, 256 thr, 64 KB LDS dbuf, 2 blocks/CU, global_load_lds
// staging with A xsw swizzle + B slot involution.
// ---------------------------------------------------------------------------
#define NCH 16   // K chunks (1024 / 64)

__global__ __launch_bounds__(256, 2) void qkv_proj(
        const float* __restrict__ x,
        const unsigned short* __restrict__ Wtf,
        unsigned short* __restrict__ Qf,
        unsigned short* __restrict__ Kf,
        unsigned short* __restrict__ Vf) {
    __shared__ __attribute__((aligned(16))) char smem[65536];   // 64 KB
    // A buffers: 2 x 8 KB at [0, 16K); B buffers: 2 x 24 KB at [16K, 64K)
    unsigned short* E = (unsigned short*)smem;                  // 12 KB overlay

    const int tid   = threadIdx.x;
    const int w     = tid >> 6;        // wave 0..3
    const int strip = w & 1;           // m-strip (16 rows)
    const int nh    = w >> 1;          // n-half (6 n-tiles = 96 cols)
    const int lane  = tid & 63;
    const int l16   = lane & 15;
    const int quad  = lane >> 4;
    const size_t rblk = (size_t)blockIdx.x * 32;
    const int bb    = (int)(rblk >> 11);
    const int tloc0 = (int)(rblk & (T_ - 1));
    const int t16_0 = tloc0 >> 4;
    const int s32_0 = tloc0 >> 5;
    const int xsw   = l16 & 7;
    // B slot involution p(s) = s ^ (s>>3); for s = 4*l16+quad, s>>3 = l16>>1.
    const int bs8   = (((l16 * 4 + quad) ^ (l16 >> 1)) * 8);   // u16 offset

    // ---- stage chunk c into buffer c&1: 32 x 1KB issues, 8 per wave ----
    auto stage = [&](int c) {
        float* Ab = (float*)(smem + (c & 1) * 8192);
        char*  Bb = smem + 16384 + (c & 1) * 24576;
#pragma unroll
        for (int q = 0; q < 8; q++) {
            int j = w * 8 + q;                 // 0..31
            if (j < 8) {                       // A: 32x64 fp32, swz source
                int row  = j * 4 + (lane >> 4);    // 0..31 (block-local)
                int slot = lane & 15;              // 16B slot within row
                int g    = slot ^ (row & 7);       // global granule16
                gload_lds16(x + (rblk + row) * C_ + c * 64 + g * 4,
                            Ab + j * 256);
            } else {                           // B: 24 x 1KB frag blocks
                int jb = j - 8;                // 0..23
                int nt = jb >> 1, kkl = jb & 1;
                int sl = lane ^ (lane >> 3);   // source granule p(lane)
                gload_lds16(
                    (const float*)(Wtf + ((size_t)nt * 32 + c * 2 + kkl) * 512
                                   + (size_t)sl * 8),
                    (float*)(Bb + jb * 1024));
            }
        }
    };

    f32x4 acc[6];
#pragma unroll
    for (int i = 0; i < 6; i++) acc[i] = (f32x4){0.f, 0.f, 0.f, 0.f};

    stage(0);
    __syncthreads();                   // chunk 0 landed

    for (int c = 0; c < NCH; c++) {
        if (c < NCH - 1) stage(c + 1);     // flies under compute + drain

        const float* Ab = (const float*)(smem + (c & 1) * 8192)
                          + (strip * 16 + l16) * 64;
        const unsigned short* Bb =
            (const unsigned short*)(smem + 16384 + (c & 1) * 24576);
#pragma unroll
        for (int kk = 0; kk < 2; kk++) {
            int g0 = kk * 8 + quad * 2;        // granule16 of lane's A frag
            float4 f0 = *(const float4*)(Ab + ((g0    ) ^ xsw) * 4);
            float4 f1 = *(const float4*)(Ab + ((g0 + 1) ^ xsw) * 4);
            bf16x8 a0 = __builtin_bit_cast(bf16x8, cvt8(f0, f1));
#pragma unroll
            for (int i = 0; i < 6; i++) {
                bf16x8 b = load8_bf(Bb + ((nh * 6 + i) * 2 + kk) * 512 + bs8);
                acc[i] = __builtin_amdgcn_mfma_f32_16x16x32_bf16(a0, b, acc[i], 0, 0, 0);
            }
        }
        __syncthreads();   // drain; co-resident block computes meanwhile
    }

    // ---- epilogue (v10-verified): E = Q 4x512 | K 4x512 | V 4x512 ----
#pragma unroll
    for (int i = 0; i < 6; i++) {
        int nt = nh * 6 + i;
#pragma unroll
        for (int r = 0; r < 4; r++) {
            unsigned short bv = f2bf(acc[i][r]);
            int off;
            if (nt < 4) {                // Q: chunk = strip*2 + part
                off = (strip * 2 + (nt >> 1)) * 512 +
                      (quad * 4 + r) * 32 + (nt & 1) * 16 + l16;
            } else if (nt < 8) {         // K
                int nk = nt - 4;
                off = 2048 + (strip * 2 + (nk >> 1)) * 512 +
                      (quad * 4 + r) * 32 + (nk & 1) * 16 + l16;
            } else {                     // V (transposed): h-major, s minor
                int ht = nt - 8;
                off = 4096 + ht * 512 + l16 * 32 + strip * 16 + quad * 4 + r;
            }
            E[off] = bv;
        }
    }
    __syncthreads();

    // ---- copy-out (v10-verified): 12 chunks x 64 granules; 3/thread ----
#pragma unroll
    for (int c3 = 0; c3 < 3; c3++) {
        int gi = c3 * 256 + tid;         // 0..767
        int ch = gi >> 6;
        int g  = gi & 63;
        unsigned short* dst;
        if (ch < 4) {
            dst = Qf + ((size_t)(bb * 128 + t16_0 + (ch >> 1)) * 2 + (ch & 1)) * 512;
        } else if (ch < 8) {
            int c2 = ch - 4;
            dst = Kf + ((size_t)(bb * 128 + t16_0 + (c2 >> 1)) * 2 + (c2 & 1)) * 512;
        } else {
            dst = Vf + ((size_t)(bb * 64 + s32_0) * 4 + (ch - 8)) * 512;
        }
        *(u16x8*)(dst + g * 8) = *(const u16x8*)(&E[ch * 512 + g * 8]);
    }
}

// ---------------------------------------------------------------------------
// Kernel 2: flash attention, v9 — LOAD-BALANCED q-tile pairing (unchanged).
// 256 blocks x 512 threads; waves 0-3 do q-tile j, waves 4-7 do 63-j:
// constant ~33 tile-iters per block. XCD batch-affinity (b = blk&7).
// ---------------------------------------------------------------------------
#define PROW 33   // u32 per P^T row
#define OMS2 66   // u16 per O-merge row

__global__ __launch_bounds__(512) void attn(
        const unsigned short* __restrict__ Qf,
        const unsigned short* __restrict__ Kf,
        const unsigned short* __restrict__ Vf,
        float* __restrict__ out) {
    __shared__ unsigned int ps_[8 * 32 * PROW];     // 33.8 KB
    __shared__ unsigned short Om_[8 * 32 * OMS2];   // 33.8 KB
    __shared__ float mred_[8][32];
    __shared__ float lred_[8][32];

    const int tid  = threadIdx.x;
    const int wave = tid >> 6;            // 0..7
    const int half = wave >> 2;           // 0 = light tile j, 1 = heavy 63-j
    const int wv4  = wave & 3;            // KV-split index 0..3 within half
    const int lane = tid & 63;
    const int l16  = lane & 15;
    const int quad = lane >> 4;
    const int b    = blockIdx.x & 7;      // XCD-affinity: batch = XCD
    const int jp   = blockIdx.x >> 3;     // pair index 0..31
    const int qt32 = half ? (63 - jp) : jp;
    const int q0   = qt32 * 32;
    const int tdiag = qt32 >> 1;          // diagonal 64-key tile index

    const int loff = l16 * 32 + quad * 8;

    // Q as B-operand, two q-groups
    bf16x8 qf[2][2];
#pragma unroll
    for (int qg = 0; qg < 2; qg++) {
        const unsigned short* Qfb = Qf + (size_t)((b * 128 + qt32 * 2 + qg) * 2) * 512;
        qf[qg][0] = load8_bf(Qfb + loff);
        qf[qg][1] = load8_bf(Qfb + 512 + loff);
    }

    f32x4 o[8];   // [qg*4 + ht]
#pragma unroll
    for (int i = 0; i < 8; i++) o[i] = (f32x4){0.f, 0.f, 0.f, 0.f};
    float m_run[2] = {-1e30f, -1e30f}, l_run[2] = {0.f, 0.f};

    const float scale = 0.125f;  // 1/sqrt(H)
    const unsigned short* Kfb = Kf + (size_t)b * 128 * 1024;
    const unsigned short* Vfb = Vf + (size_t)b * 64 * 2048;
    unsigned int* Pw = &ps_[wave * 32 * PROW];

    for (int t = wv4; t <= tdiag; t += 4) {
        // V^T A-frags: contiguous 1KB loads, issued EARLY (softmax-independent)
        bf16x8 vf[8];
#pragma unroll
        for (int ks = 0; ks < 2; ks++)
#pragma unroll
            for (int ht = 0; ht < 4; ht++)
                vf[ht * 2 + ks] = load8_bf(
                    Vfb + ((size_t)(t * 2 + ks) * 4 + ht) * 512 + loff);

        // S^T = K * Q^T for both q-groups (K frags shared)
        f32x4 s[2][4];
#pragma unroll
        for (int nt = 0; nt < 4; nt++) {
            const unsigned short* kp = Kfb + (size_t)(t * 4 + nt) * 1024;
            bf16x8 kf0 = load8_bf(kp + loff);
            bf16x8 kf1 = load8_bf(kp + 512 + loff);
#pragma unroll
            for (int qg = 0; qg < 2; qg++) {
                f32x4 z = (f32x4){0.f, 0.f, 0.f, 0.f};
                z = __builtin_amdgcn_mfma_f32_16x16x32_bf16(kf0, qf[qg][0], z, 0, 0, 0);
                z = __builtin_amdgcn_mfma_f32_16x16x32_bf16(kf1, qf[qg][1], z, 0, 0, 0);
                s[qg][nt] = z;   // S^T[s = t*64+nt*16+quad*4+r][q = q0+qg*16+l16]
            }
        }

#pragma unroll
        for (int qg = 0; qg < 2; qg++)
#pragma unroll
            for (int nt = 0; nt < 4; nt++)
#pragma unroll
                for (int r = 0; r < 4; r++) s[qg][nt][r] *= scale;

        if (t == tdiag) {   // causal: mask s > q
#pragma unroll
            for (int qg = 0; qg < 2; qg++) {
                int q = q0 + qg * 16 + l16;
#pragma unroll
                for (int nt = 0; nt < 4; nt++)
#pragma unroll
                    for (int r = 0; r < 4; r++) {
                        int key = t * 64 + nt * 16 + quad * 4 + r;
                        if (key > q) s[qg][nt][r] = -1e30f;
                    }
            }
        }

        // per-lane softmax per q-group: in-lane tree + 2 cross-quad shuffles
#pragma unroll
        for (int qg = 0; qg < 2; qg++) {
            float m0 = fmaxf(fmaxf(s[qg][0][0], s[qg][0][1]), fmaxf(s[qg][0][2], s[qg][0][3]));
            float m1 = fmaxf(fmaxf(s[qg][1][0], s[qg][1][1]), fmaxf(s[qg][1][2], s[qg][1][3]));
            float m2 = fmaxf(fmaxf(s[qg][2][0], s[qg][2][1]), fmaxf(s[qg][2][2], s[qg][2][3]));
            float m3 = fmaxf(fmaxf(s[qg][3][0], s[qg][3][1]), fmaxf(s[qg][3][2], s[qg][3][3]));
            float mx = fmaxf(fmaxf(m0, m1), fmaxf(m2, m3));
            mx = fmaxf(mx, __shfl_xor(mx, 16));
            mx = fmaxf(mx, __shfl_xor(mx, 32));
            const float m_new = fmaxf(m_run[qg], mx);
            const float alpha = __expf(m_run[qg] - m_new);
            m_run[qg] = m_new;

            float rs = 0.f;
#pragma unroll
            for (int nt = 0; nt < 4; nt++) {
#pragma unroll
                for (int i = 0; i < 2; i++) {
                    float p0 = __expf(s[qg][nt][2 * i]     - m_new);
                    float p1 = __expf(s[qg][nt][2 * i + 1] - m_new);
                    rs += p0 + p1;
                    Pw[(qg * 16 + l16) * PROW + nt * 8 + quad * 2 + i] = pack2(p0, p1);
                }
            }
            rs += __shfl_xor(rs, 16);
            rs += __shfl_xor(rs, 32);
            l_run[qg] = l_run[qg] * alpha + rs;

#pragma unroll
            for (int ht = 0; ht < 4; ht++)
#pragma unroll
                for (int r = 0; r < 4; r++) o[qg * 4 + ht][r] *= alpha;
        }

        // O^T += V^T * P^T (V frags shared across q-groups)
#pragma unroll
        for (int ks = 0; ks < 2; ks++) {
#pragma unroll
            for (int qg = 0; qg < 2; qg++) {
                bf16x8 pB = __builtin_bit_cast(bf16x8,
                    *(const u16x8*)(&Pw[(qg * 16 + l16) * PROW + ks * 16 + quad * 4]));
#pragma unroll
                for (int ht = 0; ht < 4; ht++)
                    o[qg * 4 + ht] = __builtin_amdgcn_mfma_f32_16x16x32_bf16(
                        vf[ht * 2 + ks], pB, o[qg * 4 + ht], 0, 0, 0);
            }
        }
    }

    // ---- 4-way LSE merge per half (O partials bf16) ----
#pragma unroll
    for (int qg = 0; qg < 2; qg++) {
#pragma unroll
        for (int ht = 0; ht < 4; ht++)
#pragma unroll
            for (int r = 0; r < 4; r++)
                Om_[(wave * 32 + qg * 16 + l16) * OMS2 + ht * 16 + quad * 4 + r] =
                    f2bf(o[qg * 4 + ht][r]);
        if (quad == 0) {
            mred_[wave][qg * 16 + l16] = m_run[qg];
            lred_[wave][qg * 16 + l16] = l_run[qg];
        }
    }
    __syncthreads();

    // finalize: threads 0-255 -> half 0's tile, 256-511 -> half 1's tile
    const int half2 = tid >> 8;
    const int t2    = tid & 255;
    const int hcol  = t2 & 63;
    const int qr0   = t2 >> 6;   // 0..3
    const int qt32f = half2 ? (63 - jp) : jp;
    const int q0f   = qt32f * 32;
#pragma unroll
    for (int qq = 0; qq < 8; qq++) {
        const int q = qr0 + qq * 4;
        float M = -1e30f;
#pragma unroll
        for (int w = 0; w < 4; w++) M = fmaxf(M, mred_[half2 * 4 + w][q]);
        float lt = 0.f, ov = 0.f;
#pragma unroll
        for (int w = 0; w < 4; w++) {
            float e = __expf(mred_[half2 * 4 + w][q] - M);
            lt += e * lred_[half2 * 4 + w][q];
            ov += e * bf2f(Om_[((half2 * 4 + w) * 32 + q) * OMS2 + hcol]);
        }
        out[((size_t)b * T_ + q0f + q) * H_ + hcol] = ov / lt;
    }
}

// ---------------------------------------------------------------------------
extern "C" void kernel_launch(void* const* d_in, const int* in_sizes, int n_in,
                              void* d_out, int out_size, void* d_ws, size_t ws_size,
                              hipStream_t stream) {
    const float* x  = (const float*)d_in[0];
    const float* Wq = (const float*)d_in[1];
    const float* Wk = (const float*)d_in[2];
    const float* Wv = (const float*)d_in[3];
    float* out = (float*)d_out;

    unsigned short* Qf  = (unsigned short*)d_ws;
    unsigned short* Kf  = Qf + (size_t)B_ * T_ * H_;
    unsigned short* Vf  = Kf + (size_t)B_ * T_ * H_;
    unsigned short* Wtf = Vf + (size_t)B_ * T_ * H_;

    cast_weights<<<2048, 256, 0, stream>>>(Wq, Wk, Wv, Wtf, x);
    qkv_proj<<<B_ * T_ / 32, 256, 0, stream>>>(x, Wtf, Qf, Kf, Vf);
    attn<<<B_ * (T_ / 64), 512, 0, stream>>>(Qf, Kf, Vf, out);
}